// Round 14
// baseline (673.969 us; speedup 1.0000x reference)
//
#include <hip/hip_runtime.h>
#include <hip/hip_bf16.h>

// ---------------------------------------------------------------------------
// GINE 2-layer GNN, MI355X (gfx950)  — round 14
// R13 post-mortem: (1) x-burst before eattr delayed the MFMA critical path;
// (2) (r>>1)&7 swizzle measured worse than r&7 (4.4M vs 2.4M conflicts);
// readback 8-way is inherent (full-row reads) and second-order.
// Changes:
//  1. edgem: eattr staging FIRST, x row-gather second; swizzle s^=(r&7).
//  2. bnstats fused into ngemm (wave shfl-reduce + 64 atomics/wave);
//     bnfinal fused into ngemm_bn (sc/sh recomputed per lane from sums).
//  3. xcast merged into prep. 19 -> 14 launches, -25.6MB re-read.
// ---------------------------------------------------------------------------

typedef short bhalf4 __attribute__((ext_vector_type(4)));
typedef short short8 __attribute__((ext_vector_type(8)));
typedef float f32x4 __attribute__((ext_vector_type(4)));
typedef float f32x2 __attribute__((ext_vector_type(2)));

__device__ __forceinline__ short f2bf(float x) {
    unsigned u = __float_as_uint(x);
    unsigned r = (u + 0x7fffu + ((u >> 16) & 1u)) >> 16;   // RTNE
    return (short)r;
}
__device__ __forceinline__ float bf2f(unsigned short u) {
    return __uint_as_float(((unsigned)u) << 16);
}

// ---------------------------------------------------------------------------
// Counting sort of edges by dst -> inv (edge id -> sorted pos), offs (CSR)
// ---------------------------------------------------------------------------
__global__ __launch_bounds__(256) void hist_kernel(
    const int* __restrict__ ei, int* __restrict__ cnt, int E)
{
    int e = blockIdx.x * 256 + threadIdx.x;
    if (e < E) atomicAdd(&cnt[ei[E + e]], 1);
}

__global__ __launch_bounds__(1024) void scan_kernel(
    const int* __restrict__ cnt, int* __restrict__ offs,
    int* __restrict__ cursor, int N)
{
    __shared__ int wsum[16];
    __shared__ int chunk_base;
    int tid = threadIdx.x;
    int lane = tid & 63, wid = tid >> 6;
    if (tid == 0) chunk_base = 0;
    __syncthreads();
    for (int start = 0; start < N; start += 1024) {
        int i = start + tid;
        int v = (i < N) ? cnt[i] : 0;
        int s = v;
#pragma unroll
        for (int d = 1; d < 64; d <<= 1) {
            int t = __shfl_up(s, d);
            if (lane >= d) s += t;
        }
        if (lane == 63) wsum[wid] = s;
        __syncthreads();
        int wbase = 0;
        for (int w = 0; w < wid; ++w) wbase += wsum[w];
        int excl = chunk_base + wbase + s - v;
        if (i < N) { offs[i] = excl; cursor[i] = excl; }
        int tot = 0;
        for (int w = 0; w < 16; ++w) tot += wsum[w];
        __syncthreads();
        if (tid == 0) chunk_base += tot;
        __syncthreads();
    }
    if (threadIdx.x == 0) offs[N] = chunk_base;
}

__global__ __launch_bounds__(256) void scatter_kernel(
    const int* __restrict__ ei, int* __restrict__ cursor,
    int* __restrict__ inv, int E)
{
    int e = blockIdx.x * 256 + threadIdx.x;
    if (e >= E) return;
    int d = ei[E + e];
    int pos = atomicAdd(&cursor[d], 1);
    inv[e] = pos;
}

// ---------------------------------------------------------------------------
// prep: weights f32->bf16 + x->bf16 cast (grid-stride), one launch
// ---------------------------------------------------------------------------
__global__ __launch_bounds__(256) void prep_kernel(
    const float* __restrict__ We0, const float* __restrict__ W1_0,
    const float* __restrict__ We1, const float* __restrict__ W1_1,
    const float* __restrict__ W2_0, const float* __restrict__ W2_1,
    short* __restrict__ WeB0, short* __restrict__ W1B0,
    short* __restrict__ WeB1, short* __restrict__ W1B1,
    short* __restrict__ W2B0, short* __restrict__ W2B1,
    const float* __restrict__ x, unsigned short* __restrict__ xb, int total)
{
    int i = blockIdx.x * 256 + threadIdx.x;
    if (i < 128 * 64) WeB0[i] = f2bf(We0[i]);
    if (i < 64 * 128) W1B0[i] = f2bf(W1_0[i]);
    if (i < 64 * 64) {
        WeB1[i] = f2bf(We1[i]);
        W1B1[i] = f2bf(W1_1[i]);
        W2B0[i] = f2bf(W2_0[i]);
        W2B1[i] = f2bf(W2_1[i]);
    }
    for (int k = i; k < total; k += gridDim.x * 256)
        xb[k] = (unsigned short)f2bf(x[k]);
}

// ---------------------------------------------------------------------------
// Edge kernel: m[e][f] = relu((eattr @ We^T)[e][f] + be[f] + x[src(e)][f])
// Wave = 16 edges; single cm tile, swizzle phys_slot = logical ^ (row&7)
// (low 3 bits); coalesced global I/O; eattr staged FIRST (MFMA path).
// ---------------------------------------------------------------------------
template<int DF>
__global__ __launch_bounds__(256) void edgem_kernel(
    const unsigned short* __restrict__ xb,   // [N][DF] bf16 node feats
    const int*    __restrict__ ei,           // [2][E] (src used)
    const float*  __restrict__ eattr,        // [E][64]
    const short*  __restrict__ WB,           // [DF][64] bf16 (We native)
    const float*  __restrict__ be,           // [DF]
    const int*    __restrict__ inv,          // [E] edge -> sorted pos
    unsigned short* __restrict__ pbuf,       // [E][DF] bf16 (sorted rows)
    int E)
{
    constexpr int FC  = DF / 16;
    constexpr int LPR = DF / 8;    // lanes (16B slots) per row
    constexpr int RPI = 64 / LPR;  // rows per instruction
    constexpr int NI  = 16 / RPI;  // instructions for 16 rows
    __shared__ short cm[4][16][DF];
    const int wave = threadIdx.x >> 6;
    const int lane = threadIdx.x & 63;
    const int ebase = (blockIdx.x * 4 + wave) * 16;
    if (ebase >= E) return;
    const int g = lane >> 4, c = lane & 15;
    short* ct = &cm[wave][0][0];
    auto sw = [](int s, int r) { return s ^ (r & 7); };

    // ---- burst 1: eattr coalesced -> cm staging (swizzled) ----
    {
        int r = lane >> 2, q = lane & 3;
        int e = ebase + r;
        const float* src = eattr + (size_t)((e < E) ? e : (E - 1)) * 64;
#pragma unroll
        for (int i = 0; i < 4; ++i) {
            f32x4 v = *(const f32x4*)(src + i * 16 + q * 4);
            bhalf4 b;
            b[0] = f2bf(v[0]); b[1] = f2bf(v[1]); b[2] = f2bf(v[2]); b[3] = f2bf(v[3]);
            int s = i * 2 + (q >> 1), h = q & 1;
            *(bhalf4*)(ct + r * DF + sw(s, r) * 8 + h * 4) = b;
        }
    }

    // ---- burst 2: x row slices -> regs; inv -> spos ----
    int spos[NI], rr[NI], qq[NI];
    short8 xrv[NI];
#pragma unroll
    for (int i = 0; i < NI; ++i) {
        int r = i * RPI + lane / LPR;
        int q = lane % LPR;
        rr[i] = r; qq[i] = q;
        int e = ebase + r;
        bool v = e < E;
        int es = v ? e : (E - 1);
        spos[i] = v ? inv[es] : -1;
        int se = ei[es];
        xrv[i] = *(const short8*)(xb + (size_t)se * DF + q * 8);
    }
    asm volatile("s_waitcnt lgkmcnt(0)" ::: "memory");
    __builtin_amdgcn_sched_barrier(0);

    // ---- B-frags from cm (logical slots g, g+4 of row c) ----
    short8 bfr0 = *(const short8*)(ct + c * DF + sw(g, c) * 8);
    short8 bfr1 = *(const short8*)(ct + c * DF + sw(g + 4, c) * 8);

    // ---- MFMA all chunks into regs ----
    f32x4 acc[FC];
#pragma unroll
    for (int fc = 0; fc < FC; ++fc) {
        const short* aw = WB + (size_t)(fc * 16 + c) * 64 + g * 8;
        short8 aw0 = *(const short8*)(aw);
        short8 aw1 = *(const short8*)(aw + 32);
        f32x4 a = {0.f, 0.f, 0.f, 0.f};
        a = __builtin_amdgcn_mfma_f32_16x16x32_bf16(aw0, bfr0, a, 0, 0, 0);
        a = __builtin_amdgcn_mfma_f32_16x16x32_bf16(aw1, bfr1, a, 0, 0, 0);
        acc[fc] = a;
    }

    // ---- C-transpose: lane (g,c) writes (acc+be) chunks to row c ----
    // (safe: acc depends on B-frag reads, so eattr-region reads completed)
#pragma unroll
    for (int fc = 0; fc < FC; ++fc) {
        f32x4 bev = *(const f32x4*)(be + fc * 16 + g * 4);
        bhalf4 mo;
#pragma unroll
        for (int r = 0; r < 4; ++r)
            mo[r] = f2bf(acc[fc][r] + bev[r]);
        int s = fc * 2 + (g >> 1), h = g & 1;
        *(bhalf4*)(ct + c * DF + sw(s, c) * 8 + h * 4) = mo;
    }
    asm volatile("s_waitcnt lgkmcnt(0)" ::: "memory");
    __builtin_amdgcn_sched_barrier(0);

    // ---- readback rows + x-add + relu -> row-contiguous stores ----
#pragma unroll
    for (int i = 0; i < NI; ++i) {
        int r = rr[i], q = qq[i];
        short8 v = *(const short8*)(ct + r * DF + sw(q, r) * 8);
        short8 o;
#pragma unroll
        for (int j = 0; j < 8; ++j) {
            float f = bf2f((unsigned short)v[j]) + bf2f((unsigned short)xrv[i][j]);
            o[j] = f2bf(fmaxf(f, 0.f));
        }
        if (spos[i] >= 0)
            *(short8*)(pbuf + (size_t)spos[i] * DF + q * 8) = o;
    }
}

// ---------------------------------------------------------------------------
// L0 gather-sum (streaming, DF=128): sb[n][k] = bf16(x[n][k] + sum_i pbuf[i][k])
// ---------------------------------------------------------------------------
__global__ __launch_bounds__(256) void gathersum0_kernel(
    const unsigned short* __restrict__ pbuf,   // [E][128] sorted rows
    const int* __restrict__ offs,
    const float* __restrict__ x,               // [N][128] f32
    unsigned short* __restrict__ sb, int N)
{
    int wid = threadIdx.x >> 6, lane = threadIdx.x & 63;
    int n = blockIdx.x * 4 + wid;
    if (n >= N) return;
    f32x2 xx = *(const f32x2*)(x + (size_t)n * 128 + 2 * lane);
    float s0 = xx[0], s1 = xx[1];
    int i0 = offs[n], i1 = offs[n + 1];
    const unsigned int* p = (const unsigned int*)(pbuf + (size_t)i0 * 128) + lane;
    int cnt = i1 - i0;
    int i = 0;
    for (; i + 3 < cnt; i += 4) {
        unsigned int v0 = p[0], v1 = p[64], v2 = p[128], v3 = p[192];
        s0 += bf2f((unsigned short)v0) + bf2f((unsigned short)v1)
            + bf2f((unsigned short)v2) + bf2f((unsigned short)v3);
        s1 += bf2f((unsigned short)(v0 >> 16)) + bf2f((unsigned short)(v1 >> 16))
            + bf2f((unsigned short)(v2 >> 16)) + bf2f((unsigned short)(v3 >> 16));
        p += 256;
    }
    for (; i < cnt; ++i) {
        unsigned int v = p[0];
        s0 += bf2f((unsigned short)v);
        s1 += bf2f((unsigned short)(v >> 16));
        p += 64;
    }
    unsigned int packed = (unsigned int)(unsigned short)f2bf(s0)
                        | ((unsigned int)(unsigned short)f2bf(s1) << 16);
    *(unsigned int*)(sb + (size_t)n * 128 + 2 * lane) = packed;
}

// ---------------------------------------------------------------------------
// L1 gather-sum (streaming, DF=64): sb[n][k] = bf16(y0[n][k] + sum_i pbuf[i][k])
// ---------------------------------------------------------------------------
__global__ __launch_bounds__(256) void gathersum1_kernel(
    const unsigned short* __restrict__ pbuf,   // [E][64] sorted rows
    const int* __restrict__ offs,
    const float* __restrict__ y0, unsigned short* __restrict__ sb, int N)
{
    int wid = threadIdx.x >> 6, lane = threadIdx.x & 63;
    int n = blockIdx.x * 4 + wid;
    if (n >= N) return;
    float s = y0[(size_t)n * 64 + lane];
    int i0 = offs[n], i1 = offs[n + 1];
    const unsigned short* p = pbuf + (size_t)i0 * 64 + lane;
    int cnt = i1 - i0;
    int i = 0;
    for (; i + 3 < cnt; i += 4) {
        s += bf2f(p[0]) + bf2f(p[64]) + bf2f(p[128]) + bf2f(p[192]);
        p += 256;
    }
    for (; i < cnt; ++i) { s += bf2f(p[0]); p += 64; }
    sb[(size_t)n * 64 + lane] = (unsigned short)f2bf(s);
}

// ---------------------------------------------------------------------------
// Node-tile MFMA GEMM + fused BN-stats:
//   out[n][f] = b[f] + sum_k A[n][k]*W[f][k];  sums[f] += out, sums[64+f] += out^2
// Wave reduce over g-lanes (shfl_xor 16,32) -> 64 atomics/wave per moment.
// ---------------------------------------------------------------------------
template<int DIN>
__global__ __launch_bounds__(256) void ngemm_kernel(
    const unsigned short* __restrict__ A,
    const short* __restrict__ W, const float* __restrict__ b,
    float* __restrict__ out, float* __restrict__ sums, int N)
{
    constexpr int KK = DIN / 32;
    const int wave = threadIdx.x >> 6;
    const int lane = threadIdx.x & 63;
    const int nbase = (blockIdx.x * 4 + wave) * 16;
    if (nbase >= N) return;
    const int g = lane >> 4, c = lane & 15;

    int rowc = nbase + c; if (rowc >= N) rowc = N - 1;
    const unsigned short* arow = A + (size_t)rowc * DIN + g * 8;
    short8 afr[KK];
#pragma unroll
    for (int kk = 0; kk < KK; ++kk)
        afr[kk] = *(const short8*)(arow + kk * 32);

#pragma unroll
    for (int cc = 0; cc < 4; ++cc) {
        const float bev = b[cc * 16 + c];
        f32x4 acc = {bev, bev, bev, bev};
#pragma unroll
        for (int kk = 0; kk < KK; ++kk) {
            short8 bw = *(const short8*)(W + (size_t)(cc * 16 + c) * DIN + kk * 32 + g * 8);
            acc = __builtin_amdgcn_mfma_f32_16x16x32_bf16(afr[kk], bw, acc, 0, 0, 0);
        }
        float sv = 0.f, qv = 0.f;
#pragma unroll
        for (int r = 0; r < 4; ++r) {
            int row = nbase + g * 4 + r;
            if (row < N) {
                float v = acc[r];
                out[(size_t)row * 64 + cc * 16 + c] = v;
                sv += v; qv += v * v;
            }
        }
        sv += __shfl_xor(sv, 16); sv += __shfl_xor(sv, 32);
        qv += __shfl_xor(qv, 16); qv += __shfl_xor(qv, 32);
        if (g == 0) {
            atomicAdd(&sums[cc * 16 + c], sv);
            atomicAdd(&sums[64 + cc * 16 + c], qv);
        }
    }
}

// ---------------------------------------------------------------------------
// Node-tile MFMA GEMM with fused BN-final + BN-apply + relu on the A side:
//   sc[k] = gam[k]*rsqrt(var[k]+eps); sh[k] = bet[k]-mean[k]*sc[k]
//   h[n][k] = relu(t[n][k]*sc+sh); out = h @ W2^T + b2 (+relu +bf16 emit)
// ---------------------------------------------------------------------------
__global__ __launch_bounds__(256) void ngemm_bn_kernel(
    const float* __restrict__ t, const float* __restrict__ sums,
    const float* __restrict__ gam, const float* __restrict__ bet,
    const short* __restrict__ W2, const float* __restrict__ b2,
    float* __restrict__ out, unsigned short* __restrict__ outb,
    int N, int relu_out, float invN)
{
    const int wave = threadIdx.x >> 6;
    const int lane = threadIdx.x & 63;
    const int nbase = (blockIdx.x * 4 + wave) * 16;
    if (nbase >= N) return;
    const int g = lane >> 4, c = lane & 15;

    int rowc = nbase + c; if (rowc >= N) rowc = N - 1;
    const float* trow = t + (size_t)rowc * 64 + g * 8;

    short8 afr[2];
#pragma unroll
    for (int kk = 0; kk < 2; ++kk) {
        f32x4 q0 = *(const f32x4*)(trow + kk * 32);
        f32x4 q1 = *(const f32x4*)(trow + kk * 32 + 4);
        const int kbase = kk * 32 + g * 8;
#pragma unroll
        for (int j = 0; j < 8; ++j) {
            int f = kbase + j;
            float mean = sums[f] * invN;
            float var  = sums[64 + f] * invN - mean * mean;
            float sc = gam[f] * rsqrtf(var + 1e-5f);
            float sh = bet[f] - mean * sc;
            float q = (j < 4) ? q0[j] : q1[j - 4];
            afr[kk][j] = f2bf(fmaxf(q * sc + sh, 0.f));
        }
    }

#pragma unroll
    for (int cc = 0; cc < 4; ++cc) {
        const float bev = b2[cc * 16 + c];
        f32x4 acc = {bev, bev, bev, bev};
#pragma unroll
        for (int kk = 0; kk < 2; ++kk) {
            short8 bw = *(const short8*)(W2 + (size_t)(cc * 16 + c) * 64 + kk * 32 + g * 8);
            acc = __builtin_amdgcn_mfma_f32_16x16x32_bf16(afr[kk], bw, acc, 0, 0, 0);
        }
#pragma unroll
        for (int r = 0; r < 4; ++r) {
            int row = nbase + g * 4 + r;
            if (row < N) {
                float v = acc[r];
                if (relu_out) {
                    v = fmaxf(v, 0.f);
                    outb[(size_t)row * 64 + cc * 16 + c] = (unsigned short)f2bf(v);
                }
                out[(size_t)row * 64 + cc * 16 + c] = v;
            }
        }
    }
}

extern "C" void kernel_launch(void* const* d_in, const int* in_sizes, int n_in,
                              void* d_out, int out_size, void* d_ws, size_t ws_size,
                              hipStream_t stream)
{
    (void)n_in; (void)out_size; (void)ws_size;
    const float* x     = (const float*)d_in[0];
    const int*   ei    = (const int*)d_in[1];
    const float* eattr = (const float*)d_in[2];
    const float* We0   = (const float*)d_in[3];
    const float* be0   = (const float*)d_in[4];
    const float* W1_0  = (const float*)d_in[5];
    const float* b1_0  = (const float*)d_in[6];
    const float* g0    = (const float*)d_in[7];
    const float* bb0   = (const float*)d_in[8];
    const float* W2_0  = (const float*)d_in[9];
    const float* b2_0  = (const float*)d_in[10];
    const float* We1   = (const float*)d_in[11];
    const float* be1   = (const float*)d_in[12];
    const float* W1_1  = (const float*)d_in[13];
    const float* b1_1  = (const float*)d_in[14];
    const float* g1    = (const float*)d_in[15];
    const float* bb1   = (const float*)d_in[16];
    const float* W2_1  = (const float*)d_in[17];
    const float* b2_1  = (const float*)d_in[18];
    float* out = (float*)d_out;

    const int N = in_sizes[0] / 128;   // 50000
    const int E = in_sizes[2] / 64;    // 800000

    char* ws = (char*)d_ws;
    size_t o = 0;
    auto alloc = [&](size_t bytes) { char* p = ws + o; o = (o + bytes + 255) & ~(size_t)255; return p; };
    unsigned short* pbuf = (unsigned short*)alloc((size_t)E * 128 * 2);  // L0: [E][128]; L1 reuses as [E][64]
    float* tbuf   = (float*)alloc((size_t)N * 64 * 4);
    float* y0     = (float*)alloc((size_t)N * 64 * 4);
    unsigned short* xb = (unsigned short*)alloc((size_t)N * 128 * 2);   // also sb0 (after edgem<128>)
    unsigned short* yb = (unsigned short*)alloc((size_t)N * 64 * 2);    // also sb1 (after edgem<64>)
    short* WeB0   = (short*)alloc(128 * 64 * 2);
    short* W1B0   = (short*)alloc(64 * 128 * 2);
    short* WeB1   = (short*)alloc(64 * 64 * 2);
    short* W1B1   = (short*)alloc(64 * 64 * 2);
    short* W2B0   = (short*)alloc(64 * 64 * 2);
    short* W2B1   = (short*)alloc(64 * 64 * 2);
    float* stats  = (float*)alloc(512 * 4);
    int*   cnt    = (int*)alloc((size_t)N * 4);
    int*   offs   = (int*)alloc((size_t)(N + 1) * 4);
    int*   inv    = (int*)alloc((size_t)E * 4);
    float* sum0  = stats;          // [128]: sum + sumsq
    float* sum1  = stats + 128;    // [128]
    unsigned short* sb0 = xb;   // alias: written after edgem<128> consumed xb
    unsigned short* sb1 = yb;   // alias: written after edgem<64> consumed yb

    (void)hipMemsetAsync(stats, 0, 512 * 4, stream);
    (void)hipMemsetAsync(cnt, 0, (size_t)N * 4, stream);
    prep_kernel<<<2048, 256, 0, stream>>>(We0, W1_0, We1, W1_1, W2_0, W2_1,
                                          WeB0, W1B0, WeB1, W1B1, W2B0, W2B1,
                                          x, xb, N * 128);

    const int eb256 = (E + 255) / 256;

    // ----- CSR by dst (offs) + edge -> sorted-position map (inv) -----
    hist_kernel<<<eb256, 256, 0, stream>>>(ei, cnt, E);
    scan_kernel<<<1, 1024, 0, stream>>>(cnt, offs, cnt, N);
    scatter_kernel<<<eb256, 256, 0, stream>>>(ei, cnt, inv, E);

    const int edge_blocks = ((E + 15) / 16 + 3) / 4;
    const int n4_blocks   = (N + 3) / 4;
    const int nt_blocks   = ((N + 15) / 16 + 3) / 4;

    // ----- layer 0 -----
    edgem_kernel<128><<<edge_blocks, 256, 0, stream>>>(
        xb, ei, eattr, WeB0, be0, inv, pbuf, E);
    gathersum0_kernel<<<n4_blocks, 256, 0, stream>>>(pbuf, offs, x, sb0, N);
    ngemm_kernel<128><<<nt_blocks, 256, 0, stream>>>(sb0, W1B0, b1_0, tbuf, sum0, N);
    ngemm_bn_kernel<<<nt_blocks, 256, 0, stream>>>(
        tbuf, sum0, g0, bb0, W2B0, b2_0, y0, yb, N, 1, 1.0f / N);

    // ----- layer 1 -----
    edgem_kernel<64><<<edge_blocks, 256, 0, stream>>>(
        yb, ei, eattr, WeB1, be1, inv, pbuf, E);
    gathersum1_kernel<<<n4_blocks, 256, 0, stream>>>(pbuf, offs, y0, sb1, N);
    ngemm_kernel<64><<<nt_blocks, 256, 0, stream>>>(sb1, W1B1, b1_1, tbuf, sum1, N);
    ngemm_bn_kernel<<<nt_blocks, 256, 0, stream>>>(
        tbuf, sum1, g1, bb1, W2B1, b2_1, out, yb, N, 0, 1.0f / N);
}

// Round 15
// 603.456 us; speedup vs baseline: 1.1168x; 1.1168x over previous
//
#include <hip/hip_runtime.h>
#include <hip/hip_bf16.h>

// ---------------------------------------------------------------------------
// GINE 2-layer GNN, MI355X (gfx950)  — round 15
// R14 post-mortem: BN fusion regressed +140us (128-address atomic hotspot
// in ngemm; per-lane BN recompute). Reverted. Edge kernel is latency-bound
// at 2.4TB/s -> extra MFMA ~free, traffic is not:
//  - L0 edge kernel regains GEMM2 (p = m @ W1^T) on the coalesced
//    structure: pbuf [E][128] -> [E][64]; -206MB round-trip.
//  - xw1 = xb@W1B0^T via small ngemm; gather0 = stream p + xw1.
//  - L1 path unchanged (edgem<64> single-tile, gathersum1, ngemm<64>).
// ---------------------------------------------------------------------------

typedef short bhalf4 __attribute__((ext_vector_type(4)));
typedef short short8 __attribute__((ext_vector_type(8)));
typedef float f32x4 __attribute__((ext_vector_type(4)));
typedef float f32x2 __attribute__((ext_vector_type(2)));

__device__ __forceinline__ short f2bf(float x) {
    unsigned u = __float_as_uint(x);
    unsigned r = (u + 0x7fffu + ((u >> 16) & 1u)) >> 16;   // RTNE
    return (short)r;
}
__device__ __forceinline__ float bf2f(unsigned short u) {
    return __uint_as_float(((unsigned)u) << 16);
}

// ---------------------------------------------------------------------------
// Counting sort of edges by dst -> inv (edge id -> sorted pos), offs (CSR)
// ---------------------------------------------------------------------------
__global__ __launch_bounds__(256) void hist_kernel(
    const int* __restrict__ ei, int* __restrict__ cnt, int E)
{
    int e = blockIdx.x * 256 + threadIdx.x;
    if (e < E) atomicAdd(&cnt[ei[E + e]], 1);
}

__global__ __launch_bounds__(1024) void scan_kernel(
    const int* __restrict__ cnt, int* __restrict__ offs,
    int* __restrict__ cursor, int N)
{
    __shared__ int wsum[16];
    __shared__ int chunk_base;
    int tid = threadIdx.x;
    int lane = tid & 63, wid = tid >> 6;
    if (tid == 0) chunk_base = 0;
    __syncthreads();
    for (int start = 0; start < N; start += 1024) {
        int i = start + tid;
        int v = (i < N) ? cnt[i] : 0;
        int s = v;
#pragma unroll
        for (int d = 1; d < 64; d <<= 1) {
            int t = __shfl_up(s, d);
            if (lane >= d) s += t;
        }
        if (lane == 63) wsum[wid] = s;
        __syncthreads();
        int wbase = 0;
        for (int w = 0; w < wid; ++w) wbase += wsum[w];
        int excl = chunk_base + wbase + s - v;
        if (i < N) { offs[i] = excl; cursor[i] = excl; }
        int tot = 0;
        for (int w = 0; w < 16; ++w) tot += wsum[w];
        __syncthreads();
        if (tid == 0) chunk_base += tot;
        __syncthreads();
    }
    if (threadIdx.x == 0) offs[N] = chunk_base;
}

__global__ __launch_bounds__(256) void scatter_kernel(
    const int* __restrict__ ei, int* __restrict__ cursor,
    int* __restrict__ inv, int E)
{
    int e = blockIdx.x * 256 + threadIdx.x;
    if (e >= E) return;
    int d = ei[E + e];
    int pos = atomicAdd(&cursor[d], 1);
    inv[e] = pos;
}

// ---------------------------------------------------------------------------
// prep: weights f32->bf16 + x->bf16 cast (grid-stride), one launch
// ---------------------------------------------------------------------------
__global__ __launch_bounds__(256) void prep_kernel(
    const float* __restrict__ We0, const float* __restrict__ W1_0,
    const float* __restrict__ We1, const float* __restrict__ W1_1,
    const float* __restrict__ W2_0, const float* __restrict__ W2_1,
    short* __restrict__ WeB0, short* __restrict__ W1B0,
    short* __restrict__ WeB1, short* __restrict__ W1B1,
    short* __restrict__ W2B0, short* __restrict__ W2B1,
    const float* __restrict__ x, unsigned short* __restrict__ xb, int total)
{
    int i = blockIdx.x * 256 + threadIdx.x;
    if (i < 128 * 64) WeB0[i] = f2bf(We0[i]);
    if (i < 64 * 128) W1B0[i] = f2bf(W1_0[i]);
    if (i < 64 * 64) {
        WeB1[i] = f2bf(We1[i]);
        W1B1[i] = f2bf(W1_1[i]);
        W2B0[i] = f2bf(W2_0[i]);
        W2B1[i] = f2bf(W2_1[i]);
    }
    for (int k = i; k < total; k += gridDim.x * 256)
        xb[k] = (unsigned short)f2bf(x[k]);
}

// ---------------------------------------------------------------------------
// L0 edge kernel (DIN=128, fused GEMM2):
//   m = relu(eattr@We^T + be + x[src]);  p = m @ W1^T  -> pbuf[E][64]
// Wave = 16 edges; tiles: at[16][64] (eattr, then p), xm[16][128] (x, then m)
// swizzle phys16Bslot = logical ^ (row&7); coalesced global I/O.
// ---------------------------------------------------------------------------
__global__ __launch_bounds__(256) void edgem0_kernel(
    const unsigned short* __restrict__ xb,   // [N][128] bf16
    const int*    __restrict__ ei,           // [2][E] (src used)
    const float*  __restrict__ eattr,        // [E][64]
    const short*  __restrict__ WeB,          // [128][64] bf16
    const float*  __restrict__ be,           // [128]
    const short*  __restrict__ W1B,          // [64][128] bf16
    const int*    __restrict__ inv,          // [E]
    unsigned short* __restrict__ pbuf,       // [E][64] bf16 (sorted rows)
    int E)
{
    __shared__ short at_s[4][16][64];
    __shared__ short xm_s[4][16][128];
    const int wave = threadIdx.x >> 6;
    const int lane = threadIdx.x & 63;
    const int ebase = (blockIdx.x * 4 + wave) * 16;
    if (ebase >= E) return;
    const int g = lane >> 4, c = lane & 15;
    short* at = &at_s[wave][0][0];
    short* xm = &xm_s[wave][0][0];
    auto sw = [](int s, int r) { return s ^ (r & 7); };

    // ---- spos for readback rows (8 lanes/row pattern) ----
    int spos[2];
#pragma unroll
    for (int i = 0; i < 2; ++i) {
        int r = i * 8 + (lane >> 3);
        int e = ebase + r;
        spos[i] = (e < E) ? inv[e] : -1;
    }

    // ---- burst 1: eattr coalesced -> at tile (swizzled) ----
    {
        int r = lane >> 2, q = lane & 3;
        int e = ebase + r;
        const float* src = eattr + (size_t)((e < E) ? e : (E - 1)) * 64;
#pragma unroll
        for (int i = 0; i < 4; ++i) {
            f32x4 v = *(const f32x4*)(src + i * 16 + q * 4);
            bhalf4 b;
            b[0] = f2bf(v[0]); b[1] = f2bf(v[1]); b[2] = f2bf(v[2]); b[3] = f2bf(v[3]);
            int s = i * 2 + (q >> 1), h = q & 1;
            *(bhalf4*)(at + r * 64 + sw(s, r) * 8 + h * 4) = b;
        }
    }

    // ---- burst 2: x rows coalesced -> xm tile (swizzled) ----
#pragma unroll
    for (int i = 0; i < 4; ++i) {
        int r = i * 4 + (lane >> 4);   // 16 lanes per row
        int q = lane & 15;
        int e = ebase + r;
        int es = (e < E) ? e : (E - 1);
        int se = ei[es];
        short8 v = *(const short8*)(xb + (size_t)se * 128 + q * 8);
        *(short8*)(xm + r * 128 + sw(q, r) * 8) = v;
    }
    asm volatile("s_waitcnt lgkmcnt(0)" ::: "memory");
    __builtin_amdgcn_sched_barrier(0);

    // ---- B1 frags from at: row c, logical slots g, g+4 ----
    short8 bfr0 = *(const short8*)(at + c * 64 + sw(g, c) * 8);
    short8 bfr1 = *(const short8*)(at + c * 64 + sw(g + 4, c) * 8);

    // ---- GEMM1: 8 chunks of ea^T ----
    f32x4 acc[8];
#pragma unroll
    for (int fc = 0; fc < 8; ++fc) {
        const short* aw = WeB + (size_t)(fc * 16 + c) * 64 + g * 8;
        short8 aw0 = *(const short8*)(aw);
        short8 aw1 = *(const short8*)(aw + 32);
        f32x4 a = {0.f, 0.f, 0.f, 0.f};
        a = __builtin_amdgcn_mfma_f32_16x16x32_bf16(aw0, bfr0, a, 0, 0, 0);
        a = __builtin_amdgcn_mfma_f32_16x16x32_bf16(aw1, bfr1, a, 0, 0, 0);
        acc[fc] = a;
    }

    // ---- epilogue: m = relu(acc + be + x), in-place into xm ----
#pragma unroll
    for (int fc = 0; fc < 8; ++fc) {
        f32x4 bev = *(const f32x4*)(be + fc * 16 + g * 4);
        int s = fc * 2 + (g >> 1);
        short* addr = xm + c * 128 + sw(s, c) * 8 + (g & 1) * 4;
        bhalf4 xv = *(const bhalf4*)(addr);
        bhalf4 mo;
#pragma unroll
        for (int r = 0; r < 4; ++r)
            mo[r] = f2bf(fmaxf(acc[fc][r] + bev[r] + bf2f((unsigned short)xv[r]), 0.f));
        *(bhalf4*)(addr) = mo;
    }
    asm volatile("s_waitcnt lgkmcnt(0)" ::: "memory");
    __builtin_amdgcn_sched_barrier(0);

    // ---- B2 frags from xm row c: k-slice kk*32+g*8 -> slot kk*4+g ----
    short8 b2[4];
#pragma unroll
    for (int kk = 0; kk < 4; ++kk)
        b2[kk] = *(const short8*)(xm + c * 128 + sw(kk * 4 + g, c) * 8);

    // ---- GEMM2: p^T = W1 @ m^T ; write p into at tile (free after B1) ----
#pragma unroll
    for (int fc2 = 0; fc2 < 4; ++fc2) {
        f32x4 a = {0.f, 0.f, 0.f, 0.f};
#pragma unroll
        for (int kk = 0; kk < 4; ++kk) {
            short8 aw = *(const short8*)(W1B + (size_t)(fc2 * 16 + c) * 128 + kk * 32 + g * 8);
            a = __builtin_amdgcn_mfma_f32_16x16x32_bf16(aw, b2[kk], a, 0, 0, 0);
        }
        bhalf4 po;
#pragma unroll
        for (int r = 0; r < 4; ++r) po[r] = f2bf(a[r]);
        *(bhalf4*)(at + c * 64 + sw(fc2 * 2 + (g >> 1), c) * 8 + (g & 1) * 4) = po;
    }
    asm volatile("s_waitcnt lgkmcnt(0)" ::: "memory");
    __builtin_amdgcn_sched_barrier(0);

    // ---- readback p rows (8 lanes/row) -> row-contiguous stores ----
#pragma unroll
    for (int i = 0; i < 2; ++i) {
        int r = i * 8 + (lane >> 3);
        int q = lane & 7;
        short8 v = *(const short8*)(at + r * 64 + sw(q, r) * 8);
        if (spos[i] >= 0)
            *(short8*)(pbuf + (size_t)spos[i] * 64 + q * 8) = v;
    }
}

// ---------------------------------------------------------------------------
// L1 edge kernel (DF=64, no GEMM2): single cm tile (R14 structure).
// ---------------------------------------------------------------------------
template<int DF>
__global__ __launch_bounds__(256) void edgem_kernel(
    const unsigned short* __restrict__ xb,
    const int*    __restrict__ ei,
    const float*  __restrict__ eattr,
    const short*  __restrict__ WB,
    const float*  __restrict__ be,
    const int*    __restrict__ inv,
    unsigned short* __restrict__ pbuf,
    int E)
{
    constexpr int FC  = DF / 16;
    constexpr int LPR = DF / 8;
    constexpr int RPI = 64 / LPR;
    constexpr int NI  = 16 / RPI;
    __shared__ short cm[4][16][DF];
    const int wave = threadIdx.x >> 6;
    const int lane = threadIdx.x & 63;
    const int ebase = (blockIdx.x * 4 + wave) * 16;
    if (ebase >= E) return;
    const int g = lane >> 4, c = lane & 15;
    short* ct = &cm[wave][0][0];
    auto sw = [](int s, int r) { return s ^ (r & 7); };

    // burst 1: eattr coalesced -> cm staging (swizzled)
    {
        int r = lane >> 2, q = lane & 3;
        int e = ebase + r;
        const float* src = eattr + (size_t)((e < E) ? e : (E - 1)) * 64;
#pragma unroll
        for (int i = 0; i < 4; ++i) {
            f32x4 v = *(const f32x4*)(src + i * 16 + q * 4);
            bhalf4 b;
            b[0] = f2bf(v[0]); b[1] = f2bf(v[1]); b[2] = f2bf(v[2]); b[3] = f2bf(v[3]);
            int s = i * 2 + (q >> 1), h = q & 1;
            *(bhalf4*)(ct + r * DF + sw(s, r) * 8 + h * 4) = b;
        }
    }

    // burst 2: x row slices -> regs; inv -> spos
    int spos[NI], rr[NI], qq[NI];
    short8 xrv[NI];
#pragma unroll
    for (int i = 0; i < NI; ++i) {
        int r = i * RPI + lane / LPR;
        int q = lane % LPR;
        rr[i] = r; qq[i] = q;
        int e = ebase + r;
        bool v = e < E;
        int es = v ? e : (E - 1);
        spos[i] = v ? inv[es] : -1;
        int se = ei[es];
        xrv[i] = *(const short8*)(xb + (size_t)se * DF + q * 8);
    }
    asm volatile("s_waitcnt lgkmcnt(0)" ::: "memory");
    __builtin_amdgcn_sched_barrier(0);

    short8 bfr0 = *(const short8*)(ct + c * DF + sw(g, c) * 8);
    short8 bfr1 = *(const short8*)(ct + c * DF + sw(g + 4, c) * 8);

    f32x4 acc[FC];
#pragma unroll
    for (int fc = 0; fc < FC; ++fc) {
        const short* aw = WB + (size_t)(fc * 16 + c) * 64 + g * 8;
        short8 aw0 = *(const short8*)(aw);
        short8 aw1 = *(const short8*)(aw + 32);
        f32x4 a = {0.f, 0.f, 0.f, 0.f};
        a = __builtin_amdgcn_mfma_f32_16x16x32_bf16(aw0, bfr0, a, 0, 0, 0);
        a = __builtin_amdgcn_mfma_f32_16x16x32_bf16(aw1, bfr1, a, 0, 0, 0);
        acc[fc] = a;
    }

#pragma unroll
    for (int fc = 0; fc < FC; ++fc) {
        f32x4 bev = *(const f32x4*)(be + fc * 16 + g * 4);
        bhalf4 mo;
#pragma unroll
        for (int r = 0; r < 4; ++r)
            mo[r] = f2bf(acc[fc][r] + bev[r]);
        int s = fc * 2 + (g >> 1), h = g & 1;
        *(bhalf4*)(ct + c * DF + sw(s, c) * 8 + h * 4) = mo;
    }
    asm volatile("s_waitcnt lgkmcnt(0)" ::: "memory");
    __builtin_amdgcn_sched_barrier(0);

#pragma unroll
    for (int i = 0; i < NI; ++i) {
        int r = rr[i], q = qq[i];
        short8 v = *(const short8*)(ct + r * DF + sw(q, r) * 8);
        short8 o;
#pragma unroll
        for (int j = 0; j < 8; ++j) {
            float f = bf2f((unsigned short)v[j]) + bf2f((unsigned short)xrv[i][j]);
            o[j] = f2bf(fmaxf(f, 0.f));
        }
        if (spos[i] >= 0)
            *(short8*)(pbuf + (size_t)spos[i] * DF + q * 8) = o;
    }
}

// ---------------------------------------------------------------------------
// L0 gather (streaming): t[n][f] = xw1[n][f] + sum_i pbuf[i][f]   ([E][64])
// ---------------------------------------------------------------------------
__global__ __launch_bounds__(256) void gather0_kernel(
    const unsigned short* __restrict__ pbuf,
    const int* __restrict__ offs,
    const float* __restrict__ xw1, float* __restrict__ t, int N)
{
    int wid = threadIdx.x >> 6, lane = threadIdx.x & 63;
    int n = blockIdx.x * 4 + wid;
    if (n >= N) return;
    float acc = xw1[(size_t)n * 64 + lane];
    int i0 = offs[n], i1 = offs[n + 1];
    const unsigned short* p = pbuf + (size_t)i0 * 64 + lane;
    int cnt = i1 - i0;
    int i = 0;
    for (; i + 3 < cnt; i += 4) {
        acc += bf2f(p[0]) + bf2f(p[64]) + bf2f(p[128]) + bf2f(p[192]);
        p += 256;
    }
    for (; i < cnt; ++i) { acc += bf2f(p[0]); p += 64; }
    t[(size_t)n * 64 + lane] = acc;
}

// ---------------------------------------------------------------------------
// L1 gather-sum: sb[n][k] = bf16(y0[n][k] + sum_i pbuf[i][k])
// ---------------------------------------------------------------------------
__global__ __launch_bounds__(256) void gathersum1_kernel(
    const unsigned short* __restrict__ pbuf,
    const int* __restrict__ offs,
    const float* __restrict__ y0, unsigned short* __restrict__ sb, int N)
{
    int wid = threadIdx.x >> 6, lane = threadIdx.x & 63;
    int n = blockIdx.x * 4 + wid;
    if (n >= N) return;
    float s = y0[(size_t)n * 64 + lane];
    int i0 = offs[n], i1 = offs[n + 1];
    const unsigned short* p = pbuf + (size_t)i0 * 64 + lane;
    int cnt = i1 - i0;
    int i = 0;
    for (; i + 3 < cnt; i += 4) {
        s += bf2f(p[0]) + bf2f(p[64]) + bf2f(p[128]) + bf2f(p[192]);
        p += 256;
    }
    for (; i < cnt; ++i) { s += bf2f(p[0]); p += 64; }
    sb[(size_t)n * 64 + lane] = (unsigned short)f2bf(s);
}

// ---------------------------------------------------------------------------
// Node-tile MFMA GEMM: out[n][f] = b[f] + sum_k A[n][k] * W[f][k]
// ---------------------------------------------------------------------------
template<int DIN>
__global__ __launch_bounds__(256) void ngemm_kernel(
    const unsigned short* __restrict__ A,
    const short* __restrict__ W, const float* __restrict__ b,
    float* __restrict__ out, int N)
{
    constexpr int KK = DIN / 32;
    const int wave = threadIdx.x >> 6;
    const int lane = threadIdx.x & 63;
    const int nbase = (blockIdx.x * 4 + wave) * 16;
    if (nbase >= N) return;
    const int g = lane >> 4, c = lane & 15;

    int rowc = nbase + c; if (rowc >= N) rowc = N - 1;
    const unsigned short* arow = A + (size_t)rowc * DIN + g * 8;
    short8 afr[KK];
#pragma unroll
    for (int kk = 0; kk < KK; ++kk)
        afr[kk] = *(const short8*)(arow + kk * 32);

#pragma unroll
    for (int cc = 0; cc < 4; ++cc) {
        const float bev = b[cc * 16 + c];
        f32x4 acc = {bev, bev, bev, bev};
#pragma unroll
        for (int kk = 0; kk < KK; ++kk) {
            short8 bw = *(const short8*)(W + (size_t)(cc * 16 + c) * DIN + kk * 32 + g * 8);
            acc = __builtin_amdgcn_mfma_f32_16x16x32_bf16(afr[kk], bw, acc, 0, 0, 0);
        }
#pragma unroll
        for (int r = 0; r < 4; ++r) {
            int row = nbase + g * 4 + r;
            if (row < N) out[(size_t)row * 64 + cc * 16 + c] = acc[r];
        }
    }
}

// ---------------------------------------------------------------------------
// Node-tile MFMA GEMM with fused BN-apply + relu on A side (scsh-based)
// ---------------------------------------------------------------------------
__global__ __launch_bounds__(256) void ngemm_bn_kernel(
    const float* __restrict__ t, const float* __restrict__ scsh,
    const short* __restrict__ W2, const float* __restrict__ b2,
    float* __restrict__ out, unsigned short* __restrict__ outb,
    int N, int relu_out)
{
    const int wave = threadIdx.x >> 6;
    const int lane = threadIdx.x & 63;
    const int nbase = (blockIdx.x * 4 + wave) * 16;
    if (nbase >= N) return;
    const int g = lane >> 4, c = lane & 15;

    int rowc = nbase + c; if (rowc >= N) rowc = N - 1;
    const float* trow = t + (size_t)rowc * 64 + g * 8;

    short8 afr[2];
#pragma unroll
    for (int kk = 0; kk < 2; ++kk) {
        f32x4 q0 = *(const f32x4*)(trow + kk * 32);
        f32x4 q1 = *(const f32x4*)(trow + kk * 32 + 4);
        const int kbase = kk * 32 + g * 8;
        f32x4 sc0 = *(const f32x4*)(scsh + kbase);
        f32x4 sc1 = *(const f32x4*)(scsh + kbase + 4);
        f32x4 sh0 = *(const f32x4*)(scsh + 64 + kbase);
        f32x4 sh1 = *(const f32x4*)(scsh + 64 + kbase + 4);
#pragma unroll
        for (int j = 0; j < 4; ++j) {
            afr[kk][j]     = f2bf(fmaxf(q0[j] * sc0[j] + sh0[j], 0.f));
            afr[kk][j + 4] = f2bf(fmaxf(q1[j] * sc1[j] + sh1[j], 0.f));
        }
    }

#pragma unroll
    for (int cc = 0; cc < 4; ++cc) {
        const float bev = b2[cc * 16 + c];
        f32x4 acc = {bev, bev, bev, bev};
#pragma unroll
        for (int kk = 0; kk < 2; ++kk) {
            short8 bw = *(const short8*)(W2 + (size_t)(cc * 16 + c) * 64 + kk * 32 + g * 8);
            acc = __builtin_amdgcn_mfma_f32_16x16x32_bf16(afr[kk], bw, acc, 0, 0, 0);
        }
#pragma unroll
        for (int r = 0; r < 4; ++r) {
            int row = nbase + g * 4 + r;
            if (row < N) {
                float v = acc[r];
                if (relu_out) {
                    v = fmaxf(v, 0.f);
                    outb[(size_t)row * 64 + cc * 16 + c] = (unsigned short)f2bf(v);
                }
                out[(size_t)row * 64 + cc * 16 + c] = v;
            }
        }
    }
}

// ---------------------------------------------------------------------------
// BN stats + final (separate, cheap — R13 versions)
// ---------------------------------------------------------------------------
__global__ __launch_bounds__(256) void bnstats_kernel(
    const float* __restrict__ t, float* __restrict__ sums, int total)
{
    int tid = threadIdx.x;
    float s = 0.f, s2 = 0.f;
    for (int i = blockIdx.x * 256 + tid; i < total; i += gridDim.x * 256) {
        float v = t[i];
        s += v; s2 += v * v;
    }
    __shared__ float ls[256], ls2[256];
    ls[tid] = s; ls2[tid] = s2;
    __syncthreads();
    if (tid < 64) {
        s  = ls[tid]  + ls[tid + 64]  + ls[tid + 128]  + ls[tid + 192];
        s2 = ls2[tid] + ls2[tid + 64] + ls2[tid + 128] + ls2[tid + 192];
        atomicAdd(&sums[tid], s);
        atomicAdd(&sums[64 + tid], s2);
    }
}

__global__ void bnfinal_kernel(const float* __restrict__ sums,
                               const float* __restrict__ g,
                               const float* __restrict__ bb,
                               float* __restrict__ scsh, float invN)
{
    int f = threadIdx.x;  // 64 threads
    float mean = sums[f] * invN;
    float var  = sums[64 + f] * invN - mean * mean;
    float sc = g[f] * rsqrtf(var + 1e-5f);
    scsh[f] = sc;
    scsh[64 + f] = bb[f] - mean * sc;
}

extern "C" void kernel_launch(void* const* d_in, const int* in_sizes, int n_in,
                              void* d_out, int out_size, void* d_ws, size_t ws_size,
                              hipStream_t stream)
{
    (void)n_in; (void)out_size; (void)ws_size;
    const float* x     = (const float*)d_in[0];
    const int*   ei    = (const int*)d_in[1];
    const float* eattr = (const float*)d_in[2];
    const float* We0   = (const float*)d_in[3];
    const float* be0   = (const float*)d_in[4];
    const float* W1_0  = (const float*)d_in[5];
    const float* b1_0  = (const float*)d_in[6];
    const float* g0    = (const float*)d_in[7];
    const float* bb0   = (const float*)d_in[8];
    const float* W2_0  = (const float*)d_in[9];
    const float* b2_0  = (const float*)d_in[10];
    const float* We1   = (const float*)d_in[11];
    const float* be1   = (const float*)d_in[12];
    const float* W1_1  = (const float*)d_in[13];
    const float* b1_1  = (const float*)d_in[14];
    const float* g1    = (const float*)d_in[15];
    const float* bb1   = (const float*)d_in[16];
    const float* W2_1  = (const float*)d_in[17];
    const float* b2_1  = (const float*)d_in[18];
    float* out = (float*)d_out;

    const int N = in_sizes[0] / 128;   // 50000
    const int E = in_sizes[2] / 64;    // 800000

    char* ws = (char*)d_ws;
    size_t o = 0;
    auto alloc = [&](size_t bytes) { char* p = ws + o; o = (o + bytes + 255) & ~(size_t)255; return p; };
    unsigned short* pbuf = (unsigned short*)alloc((size_t)E * 64 * 2);  // [E][64] both layers
    float* tbuf   = (float*)alloc((size_t)N * 64 * 4);
    float* y0     = (float*)alloc((size_t)N * 64 * 4);   // also xw1 (L0, pre-ngemm_bn)
    unsigned short* xb = (unsigned short*)alloc((size_t)N * 128 * 2);
    unsigned short* yb = (unsigned short*)alloc((size_t)N * 64 * 2);    // also sb1 (after edgem<64>)
    short* WeB0   = (short*)alloc(128 * 64 * 2);
    short* W1B0   = (short*)alloc(64 * 128 * 2);
    short* WeB1   = (short*)alloc(64 * 64 * 2);
    short* W1B1   = (short*)alloc(64 * 64 * 2);
    short* W2B0   = (short*)alloc(64 * 64 * 2);
    short* W2B1   = (short*)alloc(64 * 64 * 2);
    float* stats  = (float*)alloc(512 * 4);
    int*   cnt    = (int*)alloc((size_t)N * 4);
    int*   offs   = (int*)alloc((size_t)(N + 1) * 4);
    int*   inv    = (int*)alloc((size_t)E * 4);
    float* sum0  = stats;          // [128] sum+sumsq
    float* scsh0 = stats + 128;    // [128] scale+shift
    float* sum1  = stats + 256;
    float* scsh1 = stats + 384;
    float* xw1f  = y0;             // alias: consumed by gather0 before ngemm_bn writes y0
    unsigned short* sb1 = yb;      // alias: written after edgem<64> consumed yb

    (void)hipMemsetAsync(stats, 0, 512 * 4, stream);
    (void)hipMemsetAsync(cnt, 0, (size_t)N * 4, stream);
    prep_kernel<<<2048, 256, 0, stream>>>(We0, W1_0, We1, W1_1, W2_0, W2_1,
                                          WeB0, W1B0, WeB1, W1B1, W2B0, W2B1,
                                          x, xb, N * 128);

    const int eb256 = (E + 255) / 256;

    // ----- CSR by dst (offs) + edge -> sorted-position map (inv) -----
    hist_kernel<<<eb256, 256, 0, stream>>>(ei, cnt, E);
    scan_kernel<<<1, 1024, 0, stream>>>(cnt, offs, cnt, N);
    scatter_kernel<<<eb256, 256, 0, stream>>>(ei, cnt, inv, E);

    const int edge_blocks = ((E + 15) / 16 + 3) / 4;
    const int n4_blocks   = (N + 3) / 4;
    const int nt_blocks   = ((N + 15) / 16 + 3) / 4;

    // ----- layer 0 -----
    edgem0_kernel<<<edge_blocks, 256, 0, stream>>>(
        xb, ei, eattr, WeB0, be0, W1B0, inv, pbuf, E);
    ngemm_kernel<128><<<nt_blocks, 256, 0, stream>>>(xb, W1B0, b1_0, xw1f, N);
    gather0_kernel<<<n4_blocks, 256, 0, stream>>>(pbuf, offs, xw1f, tbuf, N);
    bnstats_kernel<<<256, 256, 0, stream>>>(tbuf, sum0, N * 64);
    bnfinal_kernel<<<1, 64, 0, stream>>>(sum0, g0, bb0, scsh0, 1.0f / N);
    ngemm_bn_kernel<<<nt_blocks, 256, 0, stream>>>(
        tbuf, scsh0, W2B0, b2_0, y0, yb, N, 1);

    // ----- layer 1 -----
    edgem_kernel<64><<<edge_blocks, 256, 0, stream>>>(
        yb, ei, eattr, WeB1, be1, inv, pbuf, E);
    gathersum1_kernel<<<n4_blocks, 256, 0, stream>>>(pbuf, offs, y0, sb1, N);
    ngemm_kernel<64><<<nt_blocks, 256, 0, stream>>>(sb1, W1B1, b1_1, tbuf, N);
    bnstats_kernel<<<256, 256, 0, stream>>>(tbuf, sum1, N * 64);
    bnfinal_kernel<<<1, 64, 0, stream>>>(sum1, g1, bb1, scsh1, 1.0f / N);
    ngemm_bn_kernel<<<nt_blocks, 256, 0, stream>>>(
        tbuf, scsh1, W2B1, b2_1, out, yb, N, 0);
}

// Round 16
// 555.604 us; speedup vs baseline: 1.2130x; 1.0861x over previous
//
#include <hip/hip_runtime.h>
#include <hip/hip_bf16.h>

// ---------------------------------------------------------------------------
// GINE 2-layer GNN, MI355X (gfx950)  — round 16
// R15 post-mortem: fused GEMM2 added serial phases; 100us lost for 33us of
// traffic. Edge kernel is latency-bound (all utilizations low) at every
// structure tried. R16: revert to the proven R13 pipeline; edge kernels
// process TWO independent 16-edge tiles per wave (straight-line unroll):
// 2x ILP between the two LDS fences, W-frags loaded once feed both tiles.
// ---------------------------------------------------------------------------

typedef short bhalf4 __attribute__((ext_vector_type(4)));
typedef short short8 __attribute__((ext_vector_type(8)));
typedef float f32x4 __attribute__((ext_vector_type(4)));
typedef float f32x2 __attribute__((ext_vector_type(2)));

__device__ __forceinline__ short f2bf(float x) {
    unsigned u = __float_as_uint(x);
    unsigned r = (u + 0x7fffu + ((u >> 16) & 1u)) >> 16;   // RTNE
    return (short)r;
}
__device__ __forceinline__ float bf2f(unsigned short u) {
    return __uint_as_float(((unsigned)u) << 16);
}

// ---------------------------------------------------------------------------
// Counting sort of edges by dst -> inv (edge id -> sorted pos), offs (CSR)
// ---------------------------------------------------------------------------
__global__ __launch_bounds__(256) void hist_kernel(
    const int* __restrict__ ei, int* __restrict__ cnt, int E)
{
    int e = blockIdx.x * 256 + threadIdx.x;
    if (e < E) atomicAdd(&cnt[ei[E + e]], 1);
}

__global__ __launch_bounds__(1024) void scan_kernel(
    const int* __restrict__ cnt, int* __restrict__ offs,
    int* __restrict__ cursor, int N)
{
    __shared__ int wsum[16];
    __shared__ int chunk_base;
    int tid = threadIdx.x;
    int lane = tid & 63, wid = tid >> 6;
    if (tid == 0) chunk_base = 0;
    __syncthreads();
    for (int start = 0; start < N; start += 1024) {
        int i = start + tid;
        int v = (i < N) ? cnt[i] : 0;
        int s = v;
#pragma unroll
        for (int d = 1; d < 64; d <<= 1) {
            int t = __shfl_up(s, d);
            if (lane >= d) s += t;
        }
        if (lane == 63) wsum[wid] = s;
        __syncthreads();
        int wbase = 0;
        for (int w = 0; w < wid; ++w) wbase += wsum[w];
        int excl = chunk_base + wbase + s - v;
        if (i < N) { offs[i] = excl; cursor[i] = excl; }
        int tot = 0;
        for (int w = 0; w < 16; ++w) tot += wsum[w];
        __syncthreads();
        if (tid == 0) chunk_base += tot;
        __syncthreads();
    }
    if (threadIdx.x == 0) offs[N] = chunk_base;
}

__global__ __launch_bounds__(256) void scatter_kernel(
    const int* __restrict__ ei, int* __restrict__ cursor,
    int* __restrict__ inv, int E)
{
    int e = blockIdx.x * 256 + threadIdx.x;
    if (e >= E) return;
    int d = ei[E + e];
    int pos = atomicAdd(&cursor[d], 1);
    inv[e] = pos;
}

// ---------------------------------------------------------------------------
// prep: weights f32->bf16 + x->bf16 cast (grid-stride), one launch
// ---------------------------------------------------------------------------
__global__ __launch_bounds__(256) void prep_kernel(
    const float* __restrict__ We0, const float* __restrict__ W1_0,
    const float* __restrict__ We1, const float* __restrict__ W1_1,
    const float* __restrict__ W2_0, const float* __restrict__ W2_1,
    short* __restrict__ WeB0, short* __restrict__ W1B0,
    short* __restrict__ WeB1, short* __restrict__ W1B1,
    short* __restrict__ W2B0, short* __restrict__ W2B1,
    const float* __restrict__ x, unsigned short* __restrict__ xb, int total)
{
    int i = blockIdx.x * 256 + threadIdx.x;
    if (i < 128 * 64) WeB0[i] = f2bf(We0[i]);
    if (i < 64 * 128) W1B0[i] = f2bf(W1_0[i]);
    if (i < 64 * 64) {
        WeB1[i] = f2bf(We1[i]);
        W1B1[i] = f2bf(W1_1[i]);
        W2B0[i] = f2bf(W2_0[i]);
        W2B1[i] = f2bf(W2_1[i]);
    }
    for (int k = i; k < total; k += gridDim.x * 256)
        xb[k] = (unsigned short)f2bf(x[k]);
}

// ---------------------------------------------------------------------------
// Edge kernel, 2 tiles per wave:
//   m[e][f] = relu((eattr @ We^T)[e][f] + be[f] + x[src(e)][f])
// Per tile: cm[16][DF] (eattr slots 0..7, then m); swizzle s^=(r&7).
// Phases: {stage eattr t0,t1 | x-gather t0,t1 -> regs} fence
//         {B-frags t0,t1 | MFMA (shared W) | C-writes t0,t1} fence
//         {readback + x-add + relu + sorted row stores t0,t1}
// ---------------------------------------------------------------------------
template<int DF>
__global__ __launch_bounds__(256) void edgem2_kernel(
    const unsigned short* __restrict__ xb,   // [N][DF] bf16
    const int*    __restrict__ ei,           // [2][E] (src used)
    const float*  __restrict__ eattr,        // [E][64]
    const short*  __restrict__ WB,           // [DF][64] bf16
    const float*  __restrict__ be,           // [DF]
    const int*    __restrict__ inv,          // [E]
    unsigned short* __restrict__ pbuf,       // [E][DF] bf16 (sorted rows)
    int E)
{
    constexpr int FC  = DF / 16;
    constexpr int LPR = DF / 8;
    constexpr int RPI = 64 / LPR;
    constexpr int NI  = 16 / RPI;
    __shared__ short cm[4][2][16][DF];
    const int wave = threadIdx.x >> 6;
    const int lane = threadIdx.x & 63;
    const int tbase = (blockIdx.x * 4 + wave) * 32;
    if (tbase >= E) return;
    const int g = lane >> 4, c = lane & 15;
    short* ct0 = &cm[wave][0][0][0];
    short* ct1 = &cm[wave][1][0][0];
    auto sw = [](int s, int r) { return s ^ (r & 7); };

    // ---- stage eattr, both tiles (coalesced 16 contiguous rows each) ----
    {
        int r = lane >> 2, q = lane & 3;
#pragma unroll
        for (int t = 0; t < 2; ++t) {
            short* ct = t ? ct1 : ct0;
            int e = tbase + t * 16 + r;
            const float* src = eattr + (size_t)((e < E) ? e : (E - 1)) * 64;
#pragma unroll
            for (int i = 0; i < 4; ++i) {
                f32x4 v = *(const f32x4*)(src + i * 16 + q * 4);
                bhalf4 b;
                b[0] = f2bf(v[0]); b[1] = f2bf(v[1]); b[2] = f2bf(v[2]); b[3] = f2bf(v[3]);
                int s = i * 2 + (q >> 1), h = q & 1;
                *(bhalf4*)(ct + r * DF + sw(s, r) * 8 + h * 4) = b;
            }
        }
    }

    // ---- x row slices -> regs; inv -> spos; both tiles ----
    short8 xrv[2][NI];
    int spos[2][NI];
    const int r0 = lane / LPR, qx = lane % LPR;
#pragma unroll
    for (int t = 0; t < 2; ++t) {
#pragma unroll
        for (int i = 0; i < NI; ++i) {
            int r = i * RPI + r0;
            int e = tbase + t * 16 + r;
            bool v = e < E;
            int es = v ? e : (E - 1);
            spos[t][i] = v ? inv[es] : -1;
            int se = ei[es];
            xrv[t][i] = *(const short8*)(xb + (size_t)se * DF + qx * 8);
        }
    }
    asm volatile("s_waitcnt lgkmcnt(0)" ::: "memory");
    __builtin_amdgcn_sched_barrier(0);

    // ---- B-frags both tiles (reads precede all C-writes: wave order) ----
    short8 b00 = *(const short8*)(ct0 + c * DF + sw(g, c) * 8);
    short8 b01 = *(const short8*)(ct0 + c * DF + sw(g + 4, c) * 8);
    short8 b10 = *(const short8*)(ct1 + c * DF + sw(g, c) * 8);
    short8 b11 = *(const short8*)(ct1 + c * DF + sw(g + 4, c) * 8);

    // ---- MFMA, W-frags loaded once for both tiles ----
    f32x4 acc0[FC], acc1[FC];
#pragma unroll
    for (int fc = 0; fc < FC; ++fc) {
        const short* aw = WB + (size_t)(fc * 16 + c) * 64 + g * 8;
        short8 aw0 = *(const short8*)(aw);
        short8 aw1 = *(const short8*)(aw + 32);
        f32x4 a0 = {0.f, 0.f, 0.f, 0.f};
        f32x4 a1 = {0.f, 0.f, 0.f, 0.f};
        a0 = __builtin_amdgcn_mfma_f32_16x16x32_bf16(aw0, b00, a0, 0, 0, 0);
        a1 = __builtin_amdgcn_mfma_f32_16x16x32_bf16(aw0, b10, a1, 0, 0, 0);
        a0 = __builtin_amdgcn_mfma_f32_16x16x32_bf16(aw1, b01, a0, 0, 0, 0);
        a1 = __builtin_amdgcn_mfma_f32_16x16x32_bf16(aw1, b11, a1, 0, 0, 0);
        acc0[fc] = a0; acc1[fc] = a1;
    }

    // ---- C-writes (m_pre = acc + be) both tiles ----
#pragma unroll
    for (int fc = 0; fc < FC; ++fc) {
        f32x4 bev = *(const f32x4*)(be + fc * 16 + g * 4);
        bhalf4 m0, m1;
#pragma unroll
        for (int r = 0; r < 4; ++r) {
            m0[r] = f2bf(acc0[fc][r] + bev[r]);
            m1[r] = f2bf(acc1[fc][r] + bev[r]);
        }
        int s = fc * 2 + (g >> 1), h = g & 1;
        *(bhalf4*)(ct0 + c * DF + sw(s, c) * 8 + h * 4) = m0;
        *(bhalf4*)(ct1 + c * DF + sw(s, c) * 8 + h * 4) = m1;
    }
    asm volatile("s_waitcnt lgkmcnt(0)" ::: "memory");
    __builtin_amdgcn_sched_barrier(0);

    // ---- readback + x-add + relu -> row-contiguous sorted stores ----
#pragma unroll
    for (int t = 0; t < 2; ++t) {
        short* ct = t ? ct1 : ct0;
#pragma unroll
        for (int i = 0; i < NI; ++i) {
            int r = i * RPI + r0;
            short8 v = *(const short8*)(ct + r * DF + sw(qx, r) * 8);
            short8 o;
#pragma unroll
            for (int j = 0; j < 8; ++j) {
                float f = bf2f((unsigned short)v[j]) + bf2f((unsigned short)xrv[t][i][j]);
                o[j] = f2bf(fmaxf(f, 0.f));
            }
            if (spos[t][i] >= 0)
                *(short8*)(pbuf + (size_t)spos[t][i] * DF + qx * 8) = o;
        }
    }
}

// ---------------------------------------------------------------------------
// L0 gather-sum (streaming, DF=128): sb[n][k] = bf16(x[n][k] + sum_i pbuf[i][k])
// ---------------------------------------------------------------------------
__global__ __launch_bounds__(256) void gathersum0_kernel(
    const unsigned short* __restrict__ pbuf,   // [E][128] sorted rows
    const int* __restrict__ offs,
    const float* __restrict__ x,               // [N][128] f32
    unsigned short* __restrict__ sb, int N)
{
    int wid = threadIdx.x >> 6, lane = threadIdx.x & 63;
    int n = blockIdx.x * 4 + wid;
    if (n >= N) return;
    f32x2 xx = *(const f32x2*)(x + (size_t)n * 128 + 2 * lane);
    float s0 = xx[0], s1 = xx[1];
    int i0 = offs[n], i1 = offs[n + 1];
    const unsigned int* p = (const unsigned int*)(pbuf + (size_t)i0 * 128) + lane;
    int cnt = i1 - i0;
    int i = 0;
    for (; i + 3 < cnt; i += 4) {
        unsigned int v0 = p[0], v1 = p[64], v2 = p[128], v3 = p[192];
        s0 += bf2f((unsigned short)v0) + bf2f((unsigned short)v1)
            + bf2f((unsigned short)v2) + bf2f((unsigned short)v3);
        s1 += bf2f((unsigned short)(v0 >> 16)) + bf2f((unsigned short)(v1 >> 16))
            + bf2f((unsigned short)(v2 >> 16)) + bf2f((unsigned short)(v3 >> 16));
        p += 256;
    }
    for (; i < cnt; ++i) {
        unsigned int v = p[0];
        s0 += bf2f((unsigned short)v);
        s1 += bf2f((unsigned short)(v >> 16));
        p += 64;
    }
    unsigned int packed = (unsigned int)(unsigned short)f2bf(s0)
                        | ((unsigned int)(unsigned short)f2bf(s1) << 16);
    *(unsigned int*)(sb + (size_t)n * 128 + 2 * lane) = packed;
}

// ---------------------------------------------------------------------------
// L1 gather-sum (streaming, DF=64): sb[n][k] = bf16(y0[n][k] + sum_i pbuf[i][k])
// ---------------------------------------------------------------------------
__global__ __launch_bounds__(256) void gathersum1_kernel(
    const unsigned short* __restrict__ pbuf,   // [E][64] sorted rows
    const int* __restrict__ offs,
    const float* __restrict__ y0, unsigned short* __restrict__ sb, int N)
{
    int wid = threadIdx.x >> 6, lane = threadIdx.x & 63;
    int n = blockIdx.x * 4 + wid;
    if (n >= N) return;
    float s = y0[(size_t)n * 64 + lane];
    int i0 = offs[n], i1 = offs[n + 1];
    const unsigned short* p = pbuf + (size_t)i0 * 64 + lane;
    int cnt = i1 - i0;
    int i = 0;
    for (; i + 3 < cnt; i += 4) {
        s += bf2f(p[0]) + bf2f(p[64]) + bf2f(p[128]) + bf2f(p[192]);
        p += 256;
    }
    for (; i < cnt; ++i) { s += bf2f(p[0]); p += 64; }
    sb[(size_t)n * 64 + lane] = (unsigned short)f2bf(s);
}

// ---------------------------------------------------------------------------
// Node-tile MFMA GEMM: out[n][f] = b[f] + sum_k A[n][k] * W[f][k]
// ---------------------------------------------------------------------------
template<int DIN>
__global__ __launch_bounds__(256) void ngemm_kernel(
    const unsigned short* __restrict__ A,
    const short* __restrict__ W, const float* __restrict__ b,
    float* __restrict__ out, int N)
{
    constexpr int KK = DIN / 32;
    const int wave = threadIdx.x >> 6;
    const int lane = threadIdx.x & 63;
    const int nbase = (blockIdx.x * 4 + wave) * 16;
    if (nbase >= N) return;
    const int g = lane >> 4, c = lane & 15;

    int rowc = nbase + c; if (rowc >= N) rowc = N - 1;
    const unsigned short* arow = A + (size_t)rowc * DIN + g * 8;
    short8 afr[KK];
#pragma unroll
    for (int kk = 0; kk < KK; ++kk)
        afr[kk] = *(const short8*)(arow + kk * 32);

#pragma unroll
    for (int cc = 0; cc < 4; ++cc) {
        const float bev = b[cc * 16 + c];
        f32x4 acc = {bev, bev, bev, bev};
#pragma unroll
        for (int kk = 0; kk < KK; ++kk) {
            short8 bw = *(const short8*)(W + (size_t)(cc * 16 + c) * DIN + kk * 32 + g * 8);
            acc = __builtin_amdgcn_mfma_f32_16x16x32_bf16(afr[kk], bw, acc, 0, 0, 0);
        }
#pragma unroll
        for (int r = 0; r < 4; ++r) {
            int row = nbase + g * 4 + r;
            if (row < N) out[(size_t)row * 64 + cc * 16 + c] = acc[r];
        }
    }
}

// ---------------------------------------------------------------------------
// Node-tile MFMA GEMM with fused BN-apply + relu on A side (scsh-based)
// ---------------------------------------------------------------------------
__global__ __launch_bounds__(256) void ngemm_bn_kernel(
    const float* __restrict__ t, const float* __restrict__ scsh,
    const short* __restrict__ W2, const float* __restrict__ b2,
    float* __restrict__ out, unsigned short* __restrict__ outb,
    int N, int relu_out)
{
    const int wave = threadIdx.x >> 6;
    const int lane = threadIdx.x & 63;
    const int nbase = (blockIdx.x * 4 + wave) * 16;
    if (nbase >= N) return;
    const int g = lane >> 4, c = lane & 15;

    int rowc = nbase + c; if (rowc >= N) rowc = N - 1;
    const float* trow = t + (size_t)rowc * 64 + g * 8;

    short8 afr[2];
#pragma unroll
    for (int kk = 0; kk < 2; ++kk) {
        f32x4 q0 = *(const f32x4*)(trow + kk * 32);
        f32x4 q1 = *(const f32x4*)(trow + kk * 32 + 4);
        const int kbase = kk * 32 + g * 8;
        f32x4 sc0 = *(const f32x4*)(scsh + kbase);
        f32x4 sc1 = *(const f32x4*)(scsh + kbase + 4);
        f32x4 sh0 = *(const f32x4*)(scsh + 64 + kbase);
        f32x4 sh1 = *(const f32x4*)(scsh + 64 + kbase + 4);
#pragma unroll
        for (int j = 0; j < 4; ++j) {
            afr[kk][j]     = f2bf(fmaxf(q0[j] * sc0[j] + sh0[j], 0.f));
            afr[kk][j + 4] = f2bf(fmaxf(q1[j] * sc1[j] + sh1[j], 0.f));
        }
    }

#pragma unroll
    for (int cc = 0; cc < 4; ++cc) {
        const float bev = b2[cc * 16 + c];
        f32x4 acc = {bev, bev, bev, bev};
#pragma unroll
        for (int kk = 0; kk < 2; ++kk) {
            short8 bw = *(const short8*)(W2 + (size_t)(cc * 16 + c) * 64 + kk * 32 + g * 8);
            acc = __builtin_amdgcn_mfma_f32_16x16x32_bf16(afr[kk], bw, acc, 0, 0, 0);
        }
#pragma unroll
        for (int r = 0; r < 4; ++r) {
            int row = nbase + g * 4 + r;
            if (row < N) {
                float v = acc[r];
                if (relu_out) {
                    v = fmaxf(v, 0.f);
                    outb[(size_t)row * 64 + cc * 16 + c] = (unsigned short)f2bf(v);
                }
                out[(size_t)row * 64 + cc * 16 + c] = v;
            }
        }
    }
}

// ---------------------------------------------------------------------------
// BN stats + final (separate, cheap)
// ---------------------------------------------------------------------------
__global__ __launch_bounds__(256) void bnstats_kernel(
    const float* __restrict__ t, float* __restrict__ sums, int total)
{
    int tid = threadIdx.x;
    float s = 0.f, s2 = 0.f;
    for (int i = blockIdx.x * 256 + tid; i < total; i += gridDim.x * 256) {
        float v = t[i];
        s += v; s2 += v * v;
    }
    __shared__ float ls[256], ls2[256];
    ls[tid] = s; ls2[tid] = s2;
    __syncthreads();
    if (tid < 64) {
        s  = ls[tid]  + ls[tid + 64]  + ls[tid + 128]  + ls[tid + 192];
        s2 = ls2[tid] + ls2[tid + 64] + ls2[tid + 128] + ls2[tid + 192];
        atomicAdd(&sums[tid], s);
        atomicAdd(&sums[64 + tid], s2);
    }
}

__global__ void bnfinal_kernel(const float* __restrict__ sums,
                               const float* __restrict__ g,
                               const float* __restrict__ bb,
                               float* __restrict__ scsh, float invN)
{
    int f = threadIdx.x;  // 64 threads
    float mean = sums[f] * invN;
    float var  = sums[64 + f] * invN - mean * mean;
    float sc = g[f] * rsqrtf(var + 1e-5f);
    scsh[f] = sc;
    scsh[64 + f] = bb[f] - mean * sc;
}

extern "C" void kernel_launch(void* const* d_in, const int* in_sizes, int n_in,
                              void* d_out, int out_size, void* d_ws, size_t ws_size,
                              hipStream_t stream)
{
    (void)n_in; (void)out_size; (void)ws_size;
    const float* x     = (const float*)d_in[0];
    const int*   ei    = (const int*)d_in[1];
    const float* eattr = (const float*)d_in[2];
    const float* We0   = (const float*)d_in[3];
    const float* be0   = (const float*)d_in[4];
    const float* W1_0  = (const float*)d_in[5];
    const float* b1_0  = (const float*)d_in[6];
    const float* g0    = (const float*)d_in[7];
    const float* bb0   = (const float*)d_in[8];
    const float* W2_0  = (const float*)d_in[9];
    const float* b2_0  = (const float*)d_in[10];
    const float* We1   = (const float*)d_in[11];
    const float* be1   = (const float*)d_in[12];
    const float* W1_1  = (const float*)d_in[13];
    const float* b1_1  = (const float*)d_in[14];
    const float* g1    = (const float*)d_in[15];
    const float* bb1   = (const float*)d_in[16];
    const float* W2_1  = (const float*)d_in[17];
    const float* b2_1  = (const float*)d_in[18];
    float* out = (float*)d_out;

    const int N = in_sizes[0] / 128;   // 50000
    const int E = in_sizes[2] / 64;    // 800000

    char* ws = (char*)d_ws;
    size_t o = 0;
    auto alloc = [&](size_t bytes) { char* p = ws + o; o = (o + bytes + 255) & ~(size_t)255; return p; };
    unsigned short* pbuf = (unsigned short*)alloc((size_t)E * 128 * 2);  // L0 [E][128]; L1 reuses [E][64]
    float* tbuf   = (float*)alloc((size_t)N * 64 * 4);
    float* y0     = (float*)alloc((size_t)N * 64 * 4);
    unsigned short* xb = (unsigned short*)alloc((size_t)N * 128 * 2);   // also sb0 (after edgem2<128>)
    unsigned short* yb = (unsigned short*)alloc((size_t)N * 64 * 2);    // also sb1 (after edgem2<64>)
    short* WeB0   = (short*)alloc(128 * 64 * 2);
    short* W1B0   = (short*)alloc(64 * 128 * 2);
    short* WeB1   = (short*)alloc(64 * 64 * 2);
    short* W1B1   = (short*)alloc(64 * 64 * 2);
    short* W2B0   = (short*)alloc(64 * 64 * 2);
    short* W2B1   = (short*)alloc(64 * 64 * 2);
    float* stats  = (float*)alloc(512 * 4);
    int*   cnt    = (int*)alloc((size_t)N * 4);
    int*   offs   = (int*)alloc((size_t)(N + 1) * 4);
    int*   inv    = (int*)alloc((size_t)E * 4);
    float* sum0  = stats;          // [128] sum+sumsq
    float* scsh0 = stats + 128;    // [128] scale+shift
    float* sum1  = stats + 256;
    float* scsh1 = stats + 384;
    unsigned short* sb0 = xb;   // alias: written after edgem2<128> consumed xb
    unsigned short* sb1 = yb;   // alias: written after edgem2<64> consumed yb

    (void)hipMemsetAsync(stats, 0, 512 * 4, stream);
    (void)hipMemsetAsync(cnt, 0, (size_t)N * 4, stream);
    prep_kernel<<<2048, 256, 0, stream>>>(We0, W1_0, We1, W1_1, W2_0, W2_1,
                                          WeB0, W1B0, WeB1, W1B1, W2B0, W2B1,
                                          x, xb, N * 128);

    const int eb256 = (E + 255) / 256;

    // ----- CSR by dst (offs) + edge -> sorted-position map (inv) -----
    hist_kernel<<<eb256, 256, 0, stream>>>(ei, cnt, E);
    scan_kernel<<<1, 1024, 0, stream>>>(cnt, offs, cnt, N);
    scatter_kernel<<<eb256, 256, 0, stream>>>(ei, cnt, inv, E);

    const int edge_blocks = (((E + 31) / 32) + 3) / 4;
    const int n4_blocks   = (N + 3) / 4;
    const int nt_blocks   = ((N + 15) / 16 + 3) / 4;

    // ----- layer 0 -----
    edgem2_kernel<128><<<edge_blocks, 256, 0, stream>>>(
        xb, ei, eattr, WeB0, be0, inv, pbuf, E);
    gathersum0_kernel<<<n4_blocks, 256, 0, stream>>>(pbuf, offs, x, sb0, N);
    ngemm_kernel<128><<<nt_blocks, 256, 0, stream>>>(sb0, W1B0, b1_0, tbuf, N);
    bnstats_kernel<<<256, 256, 0, stream>>>(tbuf, sum0, N * 64);
    bnfinal_kernel<<<1, 64, 0, stream>>>(sum0, g0, bb0, scsh0, 1.0f / N);
    ngemm_bn_kernel<<<nt_blocks, 256, 0, stream>>>(
        tbuf, scsh0, W2B0, b2_0, y0, yb, N, 1);

    // ----- layer 1 -----
    edgem2_kernel<64><<<edge_blocks, 256, 0, stream>>>(
        yb, ei, eattr, WeB1, be1, inv, pbuf, E);
    gathersum1_kernel<<<n4_blocks, 256, 0, stream>>>(pbuf, offs, y0, sb1, N);
    ngemm_kernel<64><<<nt_blocks, 256, 0, stream>>>(sb1, W1B1, b1_1, tbuf, N);
    bnstats_kernel<<<256, 256, 0, stream>>>(tbuf, sum1, N * 64);
    bnfinal_kernel<<<1, 64, 0, stream>>>(sum1, g1, bb1, scsh1, 1.0f / N);
    ngemm_bn_kernel<<<nt_blocks, 256, 0, stream>>>(
        tbuf, scsh1, W2B1, b2_1, out, yb, N, 0);
}

// Round 17
// 530.909 us; speedup vs baseline: 1.2695x; 1.0465x over previous
//
#include <hip/hip_runtime.h>
#include <hip/hip_bf16.h>

// ---------------------------------------------------------------------------
// GINE 2-layer GNN, MI355X (gfx950)  — round 17: exact revert to R11
// (measured best: 530.9 us). R12-R16 variants all regressed:
//   R12 (attr->regs)          184 us  — re-created global scatter
//   R13 (single tile, r>>1)   164 us  — worse swizzle, x in regs
//   R14 (BN fusion)           166/674 — atomic hotspot in ngemm
//   R15 (fused GEMM2)         259 us  — serial phases > traffic saved
//   R16 (2-tile ILP)          187 us  — VGPR 100 + 32KB LDS -> occ 21%
// R11 structure: swapped-operand MFMA; attr+xm LDS tiles with coalesced
// row-contiguous global I/O; in-place epilogue; full-row sorted stores.
// ---------------------------------------------------------------------------

typedef short bhalf4 __attribute__((ext_vector_type(4)));
typedef short short8 __attribute__((ext_vector_type(8)));
typedef float f32x4 __attribute__((ext_vector_type(4)));
typedef float f32x2 __attribute__((ext_vector_type(2)));

__device__ __forceinline__ short f2bf(float x) {
    unsigned u = __float_as_uint(x);
    unsigned r = (u + 0x7fffu + ((u >> 16) & 1u)) >> 16;   // RTNE
    return (short)r;
}
__device__ __forceinline__ float bf2f(unsigned short u) {
    return __uint_as_float(((unsigned)u) << 16);
}

// ---------------------------------------------------------------------------
// Counting sort of edges by dst -> inv (edge id -> sorted pos), offs (CSR)
// ---------------------------------------------------------------------------
__global__ __launch_bounds__(256) void hist_kernel(
    const int* __restrict__ ei, int* __restrict__ cnt, int E)
{
    int e = blockIdx.x * 256 + threadIdx.x;
    if (e < E) atomicAdd(&cnt[ei[E + e]], 1);
}

__global__ __launch_bounds__(1024) void scan_kernel(
    const int* __restrict__ cnt, int* __restrict__ offs,
    int* __restrict__ cursor, int N)
{
    __shared__ int wsum[16];
    __shared__ int chunk_base;
    int tid = threadIdx.x;
    int lane = tid & 63, wid = tid >> 6;
    if (tid == 0) chunk_base = 0;
    __syncthreads();
    for (int start = 0; start < N; start += 1024) {
        int i = start + tid;
        int v = (i < N) ? cnt[i] : 0;
        int s = v;
#pragma unroll
        for (int d = 1; d < 64; d <<= 1) {
            int t = __shfl_up(s, d);
            if (lane >= d) s += t;
        }
        if (lane == 63) wsum[wid] = s;
        __syncthreads();
        int wbase = 0;
        for (int w = 0; w < wid; ++w) wbase += wsum[w];
        int excl = chunk_base + wbase + s - v;
        if (i < N) { offs[i] = excl; cursor[i] = excl; }
        int tot = 0;
        for (int w = 0; w < 16; ++w) tot += wsum[w];
        __syncthreads();
        if (tid == 0) chunk_base += tot;
        __syncthreads();
    }
    if (threadIdx.x == 0) offs[N] = chunk_base;
}

__global__ __launch_bounds__(256) void scatter_kernel(
    const int* __restrict__ ei, int* __restrict__ cursor,
    int* __restrict__ inv, int E)
{
    int e = blockIdx.x * 256 + threadIdx.x;
    if (e >= E) return;
    int d = ei[E + e];
    int pos = atomicAdd(&cursor[d], 1);
    inv[e] = pos;
}

// ---------------------------------------------------------------------------
// x -> bf16 cast (grid-stride)
// ---------------------------------------------------------------------------
__global__ __launch_bounds__(256) void xcast_kernel(
    const float* __restrict__ x, unsigned short* __restrict__ xb, int total)
{
    for (int i = blockIdx.x * 256 + threadIdx.x; i < total; i += gridDim.x * 256)
        xb[i] = (unsigned short)f2bf(x[i]);
}

// ---------------------------------------------------------------------------
// Edge kernel (swapped-operand MFMA + LDS-staged coalesced I/O) — R11.
//   m[e][f] = relu( (eattr @ We^T)[e][f] + be[f] + x[src(e)][f] )
// Wave = 16 edges. Stores full rows at dst-sorted positions.
// ---------------------------------------------------------------------------
template<int DF>
__global__ __launch_bounds__(256) void edgem_kernel(
    const unsigned short* __restrict__ xb,   // [N][DF] bf16 node feats
    const int*    __restrict__ ei,           // [2][E] (src used)
    const float*  __restrict__ eattr,        // [E][64]
    const short*  __restrict__ WB,           // [DF][64] bf16 (We native)
    const float*  __restrict__ be,           // [DF]
    const int*    __restrict__ inv,          // [E] edge -> sorted pos
    unsigned short* __restrict__ pbuf,       // [E][DF] bf16 (sorted rows)
    int E)
{
    constexpr int FC  = DF / 16;
    constexpr int SA  = 72;        // attr tile row stride (bf16)
    constexpr int SX  = DF + 8;    // xm tile row stride (bf16)
    constexpr int LPR = DF / 8;    // lanes per row at 16B/lane
    constexpr int RPI = 64 / LPR;  // rows per instruction
    constexpr int NI  = 16 / RPI;  // instructions for 16 rows
    __shared__ short attr[4][16][SA];
    __shared__ short xm[4][16][SX];
    const int wave = threadIdx.x >> 6;
    const int lane = threadIdx.x & 63;
    const int ebase = (blockIdx.x * 4 + wave) * 16;
    if (ebase >= E) return;
    const int g = lane >> 4, c = lane & 15;
    short* at = &attr[wave][0][0];
    short* xt = &xm[wave][0][0];

    // ---- stage eattr: 4 coalesced 16B/lane loads of 16 contiguous rows ----
    {
        int r = lane >> 2, q = lane & 3;
        int e = ebase + r;
        const float* src = eattr + (size_t)((e < E) ? e : (E - 1)) * 64;
#pragma unroll
        for (int i = 0; i < 4; ++i) {
            f32x4 v = *(const f32x4*)(src + q * 4 + i * 16);
            bhalf4 b;
            b[0] = f2bf(v[0]); b[1] = f2bf(v[1]); b[2] = f2bf(v[2]); b[3] = f2bf(v[3]);
            *(bhalf4*)(at + r * SA + i * 16 + q * 4) = b;
        }
    }
    // ---- stage x[src] rows: row-contiguous 16B/lane gather ----
    {
#pragma unroll
        for (int i = 0; i < NI; ++i) {
            int r = i * RPI + lane / LPR;
            int q = lane % LPR;
            int e = ebase + r;
            int se = ei[(e < E) ? e : (E - 1)];
            short8 v = *(const short8*)(xb + (size_t)se * DF + q * 8);
            *(short8*)(xt + r * SX + q * 8) = v;
        }
    }
    asm volatile("s_waitcnt lgkmcnt(0)" ::: "memory");
    __builtin_amdgcn_sched_barrier(0);

    // ---- B-frags from attr tile ----
    short8 bfr0 = *(const short8*)(at + c * SA + g * 8);
    short8 bfr1 = *(const short8*)(at + c * SA + 32 + g * 8);

    // ---- FC chunks: 2 MFMA + epilogue (x from LDS, m back in-place) ----
#pragma unroll
    for (int fc = 0; fc < FC; ++fc) {
        const short* aw = WB + (size_t)(fc * 16 + c) * 64 + g * 8;
        short8 aw0 = *(const short8*)(aw);
        short8 aw1 = *(const short8*)(aw + 32);
        f32x4 acc = {0.f, 0.f, 0.f, 0.f};
        acc = __builtin_amdgcn_mfma_f32_16x16x32_bf16(aw0, bfr0, acc, 0, 0, 0);
        acc = __builtin_amdgcn_mfma_f32_16x16x32_bf16(aw1, bfr1, acc, 0, 0, 0);

        f32x4 bev = *(const f32x4*)(be + fc * 16 + g * 4);
        short* slot = xt + c * SX + fc * 16 + g * 4;
        bhalf4 xv = *(const bhalf4*)(slot);
        bhalf4 mo;
#pragma unroll
        for (int r = 0; r < 4; ++r) {
            float v = acc[r] + bev[r] + bf2f((unsigned short)xv[r]);
            mo[r] = f2bf(fmaxf(v, 0.f));
        }
        *(bhalf4*)(slot) = mo;
    }
    asm volatile("s_waitcnt lgkmcnt(0)" ::: "memory");
    __builtin_amdgcn_sched_barrier(0);

    // ---- store: full rows (row-contiguous 16B/lane) at sorted positions ----
    {
#pragma unroll
        for (int i = 0; i < NI; ++i) {
            int r = i * RPI + lane / LPR;
            int q = lane % LPR;
            int e = ebase + r;
            short8 v = *(const short8*)(xt + r * SX + q * 8);
            if (e < E) {
                int sp = inv[e];
                *(short8*)(pbuf + (size_t)sp * DF + q * 8) = v;
            }
        }
    }
}

// ---------------------------------------------------------------------------
// L0 gather-sum (streaming, DF=128): sb[n][k] = bf16(x[n][k] + sum_i pbuf[i][k])
// ---------------------------------------------------------------------------
__global__ __launch_bounds__(256) void gathersum0_kernel(
    const unsigned short* __restrict__ pbuf,   // [E][128] sorted rows
    const int* __restrict__ offs,
    const float* __restrict__ x,               // [N][128] f32
    unsigned short* __restrict__ sb, int N)
{
    int wid = threadIdx.x >> 6, lane = threadIdx.x & 63;
    int n = blockIdx.x * 4 + wid;
    if (n >= N) return;
    f32x2 xx = *(const f32x2*)(x + (size_t)n * 128 + 2 * lane);
    float s0 = xx[0], s1 = xx[1];
    int i0 = offs[n], i1 = offs[n + 1];
    const unsigned int* p = (const unsigned int*)(pbuf + (size_t)i0 * 128) + lane;
    int cnt = i1 - i0;
    int i = 0;
    for (; i + 3 < cnt; i += 4) {
        unsigned int v0 = p[0], v1 = p[64], v2 = p[128], v3 = p[192];
        s0 += bf2f((unsigned short)v0) + bf2f((unsigned short)v1)
            + bf2f((unsigned short)v2) + bf2f((unsigned short)v3);
        s1 += bf2f((unsigned short)(v0 >> 16)) + bf2f((unsigned short)(v1 >> 16))
            + bf2f((unsigned short)(v2 >> 16)) + bf2f((unsigned short)(v3 >> 16));
        p += 256;
    }
    for (; i < cnt; ++i) {
        unsigned int v = p[0];
        s0 += bf2f((unsigned short)v);
        s1 += bf2f((unsigned short)(v >> 16));
        p += 64;
    }
    unsigned int packed = (unsigned int)(unsigned short)f2bf(s0)
                        | ((unsigned int)(unsigned short)f2bf(s1) << 16);
    *(unsigned int*)(sb + (size_t)n * 128 + 2 * lane) = packed;
}

// ---------------------------------------------------------------------------
// L1 gather-sum (streaming, DF=64): sb[n][k] = bf16(y0[n][k] + sum_i pbuf[i][k])
// ---------------------------------------------------------------------------
__global__ __launch_bounds__(256) void gathersum1_kernel(
    const unsigned short* __restrict__ pbuf,   // [E][64] sorted rows
    const int* __restrict__ offs,
    const float* __restrict__ y0, unsigned short* __restrict__ sb, int N)
{
    int wid = threadIdx.x >> 6, lane = threadIdx.x & 63;
    int n = blockIdx.x * 4 + wid;
    if (n >= N) return;
    float s = y0[(size_t)n * 64 + lane];
    int i0 = offs[n], i1 = offs[n + 1];
    const unsigned short* p = pbuf + (size_t)i0 * 64 + lane;
    int cnt = i1 - i0;
    int i = 0;
    for (; i + 3 < cnt; i += 4) {
        s += bf2f(p[0]) + bf2f(p[64]) + bf2f(p[128]) + bf2f(p[192]);
        p += 256;
    }
    for (; i < cnt; ++i) { s += bf2f(p[0]); p += 64; }
    sb[(size_t)n * 64 + lane] = (unsigned short)f2bf(s);
}

// ---------------------------------------------------------------------------
// Node-tile MFMA GEMM: out[n][f] = b[f] + sum_k A[n][k] * W[f][k]
// ---------------------------------------------------------------------------
template<int DIN>
__global__ __launch_bounds__(256) void ngemm_kernel(
    const unsigned short* __restrict__ A,
    const short* __restrict__ W, const float* __restrict__ b,
    float* __restrict__ out, int N)
{
    constexpr int KK = DIN / 32;
    const int wave = threadIdx.x >> 6;
    const int lane = threadIdx.x & 63;
    const int nbase = (blockIdx.x * 4 + wave) * 16;
    if (nbase >= N) return;
    const int g = lane >> 4, c = lane & 15;

    int rowc = nbase + c; if (rowc >= N) rowc = N - 1;
    const unsigned short* arow = A + (size_t)rowc * DIN + g * 8;
    short8 afr[KK];
#pragma unroll
    for (int kk = 0; kk < KK; ++kk)
        afr[kk] = *(const short8*)(arow + kk * 32);

#pragma unroll
    for (int cc = 0; cc < 4; ++cc) {
        const float bev = b[cc * 16 + c];
        f32x4 acc = {bev, bev, bev, bev};
#pragma unroll
        for (int kk = 0; kk < KK; ++kk) {
            short8 bw = *(const short8*)(W + (size_t)(cc * 16 + c) * DIN + kk * 32 + g * 8);
            acc = __builtin_amdgcn_mfma_f32_16x16x32_bf16(afr[kk], bw, acc, 0, 0, 0);
        }
#pragma unroll
        for (int r = 0; r < 4; ++r) {
            int row = nbase + g * 4 + r;
            if (row < N) out[(size_t)row * 64 + cc * 16 + c] = acc[r];
        }
    }
}

// ---------------------------------------------------------------------------
// Node-tile MFMA GEMM with fused BN-apply + relu on the A side
// ---------------------------------------------------------------------------
__global__ __launch_bounds__(256) void ngemm_bn_kernel(
    const float* __restrict__ t, const float* __restrict__ scsh,
    const short* __restrict__ W2, const float* __restrict__ b2,
    float* __restrict__ out, unsigned short* __restrict__ outb,
    int N, int relu_out)
{
    const int wave = threadIdx.x >> 6;
    const int lane = threadIdx.x & 63;
    const int nbase = (blockIdx.x * 4 + wave) * 16;
    if (nbase >= N) return;
    const int g = lane >> 4, c = lane & 15;

    int rowc = nbase + c; if (rowc >= N) rowc = N - 1;
    const float* trow = t + (size_t)rowc * 64 + g * 8;

    short8 afr[2];
#pragma unroll
    for (int kk = 0; kk < 2; ++kk) {
        f32x4 q0 = *(const f32x4*)(trow + kk * 32);
        f32x4 q1 = *(const f32x4*)(trow + kk * 32 + 4);
        const int kbase = kk * 32 + g * 8;
        f32x4 sc0 = *(const f32x4*)(scsh + kbase);
        f32x4 sc1 = *(const f32x4*)(scsh + kbase + 4);
        f32x4 sh0 = *(const f32x4*)(scsh + 64 + kbase);
        f32x4 sh1 = *(const f32x4*)(scsh + 64 + kbase + 4);
#pragma unroll
        for (int j = 0; j < 4; ++j) {
            afr[kk][j]     = f2bf(fmaxf(q0[j] * sc0[j] + sh0[j], 0.f));
            afr[kk][j + 4] = f2bf(fmaxf(q1[j] * sc1[j] + sh1[j], 0.f));
        }
    }

#pragma unroll
    for (int cc = 0; cc < 4; ++cc) {
        const float bev = b2[cc * 16 + c];
        f32x4 acc = {bev, bev, bev, bev};
#pragma unroll
        for (int kk = 0; kk < 2; ++kk) {
            short8 bw = *(const short8*)(W2 + (size_t)(cc * 16 + c) * 64 + kk * 32 + g * 8);
            acc = __builtin_amdgcn_mfma_f32_16x16x32_bf16(afr[kk], bw, acc, 0, 0, 0);
        }
#pragma unroll
        for (int r = 0; r < 4; ++r) {
            int row = nbase + g * 4 + r;
            if (row < N) {
                float v = acc[r];
                if (relu_out) {
                    v = fmaxf(v, 0.f);
                    outb[(size_t)row * 64 + cc * 16 + c] = (unsigned short)f2bf(v);
                }
                out[(size_t)row * 64 + cc * 16 + c] = v;
            }
        }
    }
}

// ---------------------------------------------------------------------------
// BN stats + final
// ---------------------------------------------------------------------------
__global__ __launch_bounds__(256) void bnstats_kernel(
    const float* __restrict__ t, float* __restrict__ sums, int total)
{
    int tid = threadIdx.x;
    float s = 0.f, s2 = 0.f;
    for (int i = blockIdx.x * 256 + tid; i < total; i += gridDim.x * 256) {
        float v = t[i];
        s += v; s2 += v * v;
    }
    __shared__ float ls[256], ls2[256];
    ls[tid] = s; ls2[tid] = s2;
    __syncthreads();
    if (tid < 64) {
        s  = ls[tid]  + ls[tid + 64]  + ls[tid + 128]  + ls[tid + 192];
        s2 = ls2[tid] + ls2[tid + 64] + ls2[tid + 128] + ls2[tid + 192];
        atomicAdd(&sums[tid], s);
        atomicAdd(&sums[64 + tid], s2);
    }
}

__global__ void bnfinal_kernel(const float* __restrict__ sums,
                               const float* __restrict__ g,
                               const float* __restrict__ bb,
                               float* __restrict__ scsh, float invN)
{
    int f = threadIdx.x;  // 64 threads
    float mean = sums[f] * invN;
    float var  = sums[64 + f] * invN - mean * mean;
    float sc = g[f] * rsqrtf(var + 1e-5f);
    scsh[f] = sc;
    scsh[64 + f] = bb[f] - mean * sc;
}

// ---------------------------------------------------------------------------
// Weight prep: f32 -> bf16
// ---------------------------------------------------------------------------
__global__ __launch_bounds__(256) void prep_kernel(
    const float* __restrict__ We0, const float* __restrict__ W1_0,
    const float* __restrict__ We1, const float* __restrict__ W1_1,
    const float* __restrict__ W2_0, const float* __restrict__ W2_1,
    short* __restrict__ WeB0, short* __restrict__ W1B0,
    short* __restrict__ WeB1, short* __restrict__ W1B1,
    short* __restrict__ W2B0, short* __restrict__ W2B1)
{
    int i = blockIdx.x * 256 + threadIdx.x;
    if (i < 128 * 64) WeB0[i] = f2bf(We0[i]);
    if (i < 64 * 128) W1B0[i] = f2bf(W1_0[i]);
    if (i < 64 * 64) {
        WeB1[i] = f2bf(We1[i]);
        W1B1[i] = f2bf(W1_1[i]);
        W2B0[i] = f2bf(W2_0[i]);
        W2B1[i] = f2bf(W2_1[i]);
    }
}

extern "C" void kernel_launch(void* const* d_in, const int* in_sizes, int n_in,
                              void* d_out, int out_size, void* d_ws, size_t ws_size,
                              hipStream_t stream)
{
    (void)n_in; (void)out_size; (void)ws_size;
    const float* x     = (const float*)d_in[0];
    const int*   ei    = (const int*)d_in[1];
    const float* eattr = (const float*)d_in[2];
    const float* We0   = (const float*)d_in[3];
    const float* be0   = (const float*)d_in[4];
    const float* W1_0  = (const float*)d_in[5];
    const float* b1_0  = (const float*)d_in[6];
    const float* g0    = (const float*)d_in[7];
    const float* bb0   = (const float*)d_in[8];
    const float* W2_0  = (const float*)d_in[9];
    const float* b2_0  = (const float*)d_in[10];
    const float* We1   = (const float*)d_in[11];
    const float* be1   = (const float*)d_in[12];
    const float* W1_1  = (const float*)d_in[13];
    const float* b1_1  = (const float*)d_in[14];
    const float* g1    = (const float*)d_in[15];
    const float* bb1   = (const float*)d_in[16];
    const float* W2_1  = (const float*)d_in[17];
    const float* b2_1  = (const float*)d_in[18];
    float* out = (float*)d_out;

    const int N = in_sizes[0] / 128;   // 50000
    const int E = in_sizes[2] / 64;    // 800000

    char* ws = (char*)d_ws;
    size_t o = 0;
    auto alloc = [&](size_t bytes) { char* p = ws + o; o = (o + bytes + 255) & ~(size_t)255; return p; };
    unsigned short* pbuf = (unsigned short*)alloc((size_t)E * 128 * 2);  // L0: [E][128]; L1 reuses as [E][64]
    float* tbuf   = (float*)alloc((size_t)N * 64 * 4);
    float* y0     = (float*)alloc((size_t)N * 64 * 4);
    unsigned short* xb = (unsigned short*)alloc((size_t)N * 128 * 2);   // also sb0 (after edgem<128>)
    unsigned short* yb = (unsigned short*)alloc((size_t)N * 64 * 2);    // also sb1 (after edgem<64>)
    short* WeB0   = (short*)alloc(128 * 64 * 2);
    short* W1B0   = (short*)alloc(64 * 128 * 2);
    short* WeB1   = (short*)alloc(64 * 64 * 2);
    short* W1B1   = (short*)alloc(64 * 64 * 2);
    short* W2B0   = (short*)alloc(64 * 64 * 2);
    short* W2B1   = (short*)alloc(64 * 64 * 2);
    float* stats  = (float*)alloc(512 * 4);
    int*   cnt    = (int*)alloc((size_t)N * 4);
    int*   offs   = (int*)alloc((size_t)(N + 1) * 4);
    int*   inv    = (int*)alloc((size_t)E * 4);
    float* sum0  = stats;
    float* scsh0 = stats + 128;
    float* sum1  = stats + 256;
    float* scsh1 = stats + 384;
    unsigned short* sb0 = xb;   // alias: written after edgem<128> consumed xb
    unsigned short* sb1 = yb;   // alias: written after edgem<64> consumed yb

    (void)hipMemsetAsync(stats, 0, 512 * 4, stream);
    (void)hipMemsetAsync(cnt, 0, (size_t)N * 4, stream);
    prep_kernel<<<64, 256, 0, stream>>>(We0, W1_0, We1, W1_1, W2_0, W2_1,
                                        WeB0, W1B0, WeB1, W1B1, W2B0, W2B1);
    xcast_kernel<<<2048, 256, 0, stream>>>(x, xb, N * 128);

    const int eb256 = (E + 255) / 256;

    // ----- CSR by dst (offs) + edge -> sorted-position map (inv) -----
    hist_kernel<<<eb256, 256, 0, stream>>>(ei, cnt, E);
    scan_kernel<<<1, 1024, 0, stream>>>(cnt, offs, cnt, N);
    scatter_kernel<<<eb256, 256, 0, stream>>>(ei, cnt, inv, E);

    const int edge_blocks = ((E + 15) / 16 + 3) / 4;
    const int n4_blocks   = (N + 3) / 4;
    const int nt_blocks   = ((N + 15) / 16 + 3) / 4;

    // ----- layer 0 -----
    edgem_kernel<128><<<edge_blocks, 256, 0, stream>>>(
        xb, ei, eattr, WeB0, be0, inv, pbuf, E);
    gathersum0_kernel<<<n4_blocks, 256, 0, stream>>>(pbuf, offs, x, sb0, N);
    ngemm_kernel<128><<<nt_blocks, 256, 0, stream>>>(sb0, W1B0, b1_0, tbuf, N);
    bnstats_kernel<<<256, 256, 0, stream>>>(tbuf, sum0, N * 64);
    bnfinal_kernel<<<1, 64, 0, stream>>>(sum0, g0, bb0, scsh0, 1.0f / N);
    ngemm_bn_kernel<<<nt_blocks, 256, 0, stream>>>(
        tbuf, scsh0, W2B0, b2_0, y0, yb, N, 1);

    // ----- layer 1 -----
    edgem_kernel<64><<<edge_blocks, 256, 0, stream>>>(
        yb, ei, eattr, WeB1, be1, inv, pbuf, E);
    gathersum1_kernel<<<n4_blocks, 256, 0, stream>>>(pbuf, offs, y0, sb1, N);
    ngemm_kernel<64><<<nt_blocks, 256, 0, stream>>>(sb1, W1B1, b1_1, tbuf, N);
    bnstats_kernel<<<256, 256, 0, stream>>>(tbuf, sum1, N * 64);
    bnfinal_kernel<<<1, 64, 0, stream>>>(sum1, g1, bb1, scsh1, 1.0f / N);
    ngemm_bn_kernel<<<nt_blocks, 256, 0, stream>>>(
        tbuf, scsh1, W2B1, b2_1, out, yb, N, 0);
}